// Round 10
// baseline (1096.814 us; speedup 1.0000x reference)
//
#include <hip/hip_runtime.h>

#define T_LEN 192

// ===========================================================================
// ---- tiled GEMM body: Y[n,o,t] = sum_c W[o,c]*X[c,t] + B[o] ---------------
// ===========================================================================
template<bool TRANSX>
__device__ __forceinline__ void gemm_body(
    float* smem,
    const float* __restrict__ W, const float* __restrict__ B,
    const float* __restrict__ X, float* __restrict__ Y,
    int cin, int cstr, int ostr, int wnstr,
    int t0, int o0, int n, int tid)
{
  float (*Ws)[68] = (float(*)[68])smem;             // [c][o]
  float (*Xs)[68] = (float(*)[68])(smem + 64 * 68); // [c][t]
  const int to = tid >> 4, tt = tid & 15;
  float acc[4][4] = {};

  for (int c0 = 0; c0 < cin; c0 += 64) {
    __syncthreads();
#pragma unroll
    for (int l = 0; l < 4; ++l) {
      int idx = l * 256 + tid;
      int rr = idx >> 4, c4 = idx & 15;
      float4 wv = *reinterpret_cast<const float4*>(
          &W[(size_t)n * wnstr + (size_t)(o0 + rr) * cin + c0 + c4 * 4]);
      Ws[c4 * 4 + 0][rr] = wv.x; Ws[c4 * 4 + 1][rr] = wv.y;
      Ws[c4 * 4 + 2][rr] = wv.z; Ws[c4 * 4 + 3][rr] = wv.w;
      if (!TRANSX) {
        float4 xv = *reinterpret_cast<const float4*>(
            &X[((size_t)n * cstr + c0 + rr) * T_LEN + t0 + c4 * 4]);
        *reinterpret_cast<float4*>(&Xs[rr][c4 * 4]) = xv;
      } else {
        float4 xv = *reinterpret_cast<const float4*>(
            &X[((size_t)n * 192 + t0 + rr) * 192 + c0 + c4 * 4]);
        Xs[c4 * 4 + 0][rr] = xv.x; Xs[c4 * 4 + 1][rr] = xv.y;
        Xs[c4 * 4 + 2][rr] = xv.z; Xs[c4 * 4 + 3][rr] = xv.w;
      }
    }
    __syncthreads();
#pragma unroll
    for (int kk = 0; kk < 64; ++kk) {
      float4 a = *reinterpret_cast<const float4*>(&Ws[kk][to * 4]);
      float4 b = *reinterpret_cast<const float4*>(&Xs[kk][tt * 4]);
      acc[0][0] += a.x * b.x; acc[0][1] += a.x * b.y; acc[0][2] += a.x * b.z; acc[0][3] += a.x * b.w;
      acc[1][0] += a.y * b.x; acc[1][1] += a.y * b.y; acc[1][2] += a.y * b.z; acc[1][3] += a.y * b.w;
      acc[2][0] += a.z * b.x; acc[2][1] += a.z * b.y; acc[2][2] += a.z * b.z; acc[2][3] += a.z * b.w;
      acc[3][0] += a.w * b.x; acc[3][1] += a.w * b.y; acc[3][2] += a.w * b.z; acc[3][3] += a.w * b.w;
    }
  }
#pragma unroll
  for (int i = 0; i < 4; ++i) {
    float bi = B ? B[o0 + to * 4 + i] : 0.f;
    float4 v = make_float4(acc[i][0] + bi, acc[i][1] + bi, acc[i][2] + bi, acc[i][3] + bi);
    *reinterpret_cast<float4*>(
        &Y[((size_t)n * ostr + o0 + to * 4 + i) * T_LEN + t0 + tt * 4]) = v;
  }
}

// ===========================================================================
// foldA: parts[chunk][j*K+i][c'] = sum_{c in 16-chunk} wa[c,j]*wk[c,c',i]
// ===========================================================================
template<int K, int JN>
__device__ __forceinline__ void foldA_body(
    const float* __restrict__ wa, const float* __restrict__ wk,
    float* __restrict__ parts, int j0, int chunk, int tid)
{
  float acc[JN][K];
#pragma unroll
  for (int jj = 0; jj < JN; ++jj)
#pragma unroll
    for (int i = 0; i < K; ++i) acc[jj][i] = 0.f;

  const int c0 = chunk * 16;
  for (int c = c0; c < c0 + 16; ++c) {
    const float* base = &wk[((size_t)c * 256 + tid) * K];
    float v[K];
#pragma unroll
    for (int i = 0; i < K; ++i) v[i] = base[i];
    float w[JN];
#pragma unroll
    for (int jj = 0; jj < JN; ++jj) w[jj] = wa[c * K + j0 + jj];
#pragma unroll
    for (int jj = 0; jj < JN; ++jj)
#pragma unroll
      for (int i = 0; i < K; ++i) acc[jj][i] += w[jj] * v[i];
  }
#pragma unroll
  for (int jj = 0; jj < JN; ++jj)
#pragma unroll
    for (int i = 0; i < K; ++i)
      parts[((size_t)chunk * K * K + (j0 + jj) * K + i) * 256 + tid] = acc[jj][i];
}

// ---- cka[s,j] = sum_c wa[c,j]*bk[c] ---------------------------------------
__device__ __forceinline__ void cka_body(
    const float* __restrict__ wa0, const float* __restrict__ bk0,
    const float* __restrict__ wa1, const float* __restrict__ bk1,
    const float* __restrict__ wa2, const float* __restrict__ bk2,
    float* __restrict__ cka, int tid)
{
  if (tid >= 21) return;
  int s, j, K; const float *wa, *bk;
  if (tid < 3)       { s = 0; j = tid;      K = 3;  wa = wa0; bk = bk0; }
  else if (tid < 10) { s = 1; j = tid - 3;  K = 7;  wa = wa1; bk = bk1; }
  else               { s = 2; j = tid - 10; K = 11; wa = wa2; bk = bk2; }
  float acc = 0.f;
  for (int c = 0; c < 128; ++c) acc += wa[c * K + j] * bk[c];
  cka[s * 11 + j] = acc;
}

// ===========================================================================
// foldB: stage chunk-summed WKA row in LDS, then coalesced wp GEMV.
// half==0 block also computes bpA[ji] via LDS dot.
// ===========================================================================
template<int K>
__device__ __forceinline__ void foldB_body(
    float* lds, const float* __restrict__ parts, const float* __restrict__ wp,
    const float* __restrict__ bp, float* __restrict__ wxas,
    float* __restrict__ bpA_s, int ji, int half, int tid)
{
  constexpr int KP = (K + 3) & ~3;
  constexpr int K2 = K * K;
  float s = 0.f;
#pragma unroll
  for (int ch = 0; ch < 8; ++ch)
    s += parts[((size_t)(ch * K2 + ji)) * 256 + tid];
  lds[tid] = s;
  __syncthreads();

  const int cin = half * 256 + tid;
  float acc = 0.f;
  for (int c = 0; c < 256; ++c)
    acc += lds[c] * wp[(size_t)c * 512 + cin];
  const int j = ji / K, i = ji - j * K;
  wxas[(size_t)cin * K * KP + i * KP + j] = acc;

  if (half == 0 && tid == 0) {
    float b = 0.f;
    for (int c = 0; c < 256; ++c) b += lds[c] * bp[c];
    bpA_s[j * 11 + i] = b;
  }
}

// ===========================================================================
// rcomp: rpart[n,cc,j,t] = sum_{16ch,i} WXA[c,i,j]*xpad[n,c,t+i-A]
// ===========================================================================
template<int A>
__device__ __forceinline__ void rcomp_body(
    float* smem, const float* __restrict__ x, const float* __restrict__ WXAs,
    float* __restrict__ rps, int cc, int n, int tid)
{
  constexpr int K  = 2 * A + 1;
  constexpr int KP = (K + 3) & ~3;
  constexpr int WH = 192 + 2 * A;
  constexpr int WS = 204;
  float* Xs = smem;               // 16 x 204
  float* Wl = smem + 16 * WS;     // 16 x K x KP
  const int c0 = cc * 16;

  for (int idx = tid; idx < 16 * WH; idx += 256) {
    int c = idx / WH, p = idx - c * WH;
    int tau = p - A;
    Xs[c * WS + p] = (tau >= 0 && tau < 192)
        ? x[((size_t)n * 512 + c0 + c) * 192 + tau] : 0.f;
  }
  {
    const float4* wg = reinterpret_cast<const float4*>(WXAs + (size_t)c0 * K * KP);
    float4* wl = reinterpret_cast<float4*>(Wl);
    for (int idx = tid; idx < 16 * K * KP / 4; idx += 256) wl[idx] = wg[idx];
  }
  __syncthreads();

  const int w = tid >> 6, lane = tid & 63;
  const int csub = lane >> 4, tpos = lane & 15;
  const int tb = w * 48 + tpos * 3;

  float acc[K][3];
#pragma unroll
  for (int j = 0; j < K; ++j) { acc[j][0] = 0.f; acc[j][1] = 0.f; acc[j][2] = 0.f; }

#pragma unroll
  for (int c = 0; c < 4; ++c) {
    const int ch = csub * 4 + c;
    float win[K + 2];
#pragma unroll
    for (int p = 0; p < K + 2; ++p) win[p] = Xs[ch * WS + tb + p];
    const float* wr = &Wl[ch * K * KP];
#pragma unroll
    for (int i = 0; i < K; ++i) {
#pragma unroll
      for (int j = 0; j < K; ++j) {
        float wv = wr[i * KP + j];
        acc[j][0] += wv * win[i + 0];
        acc[j][1] += wv * win[i + 1];
        acc[j][2] += wv * win[i + 2];
      }
    }
  }
#pragma unroll
  for (int j = 0; j < K; ++j) {
#pragma unroll
    for (int q = 0; q < 3; ++q) {
      float v = acc[j][q];
      v += __shfl_xor(v, 16);
      v += __shfl_xor(v, 32);
      acc[j][q] = v;
    }
  }
  if (csub == 0) {
#pragma unroll
    for (int j = 0; j < K; ++j) {
      float* dst = &rps[(((size_t)n * 32 + cc) * K + j) * 192 + tb];
      dst[0] = acc[j][0]; dst[1] = acc[j][1]; dst[2] = acc[j][2];
    }
  }
}

// ---- rreduce: rbuf[s,n,j,t] = sum_cc rpart + cka + boundary bp term -------
__device__ __forceinline__ void rreduce_body(
    const float* __restrict__ rpart, const float* __restrict__ cka,
    const float* __restrict__ bpA, float* __restrict__ rbuf,
    int n, int sj, int t)
{
  if (t >= 192) return;
  const int s = sj < 3 ? 0 : sj < 10 ? 1 : 2;
  const int j = sj < 3 ? sj : sj < 10 ? sj - 3 : sj - 10;
  const int A = (s == 0) ? 1 : (s == 1) ? 3 : 5;
  const int K = 2 * A + 1;
  const int roff = (s == 0) ? 0 : (s == 1) ? 147456 : 491520;
  const float* rp = rpart + roff;
  float acc = cka[s * 11 + j];
#pragma unroll 8
  for (int cc = 0; cc < 32; ++cc)
    acc += rp[(((size_t)n * 32 + cc) * K + j) * 192 + t];
  for (int i = 0; i < K; ++i) {
    int tau = t + i - A;
    if (tau >= 0 && tau < 192) acc += bpA[s * 121 + j * 11 + i];
  }
  rbuf[((size_t)(s * 8 + n) * 11 + j) * 192 + t] = acc;
}

// ===========================================================================
// abuild: 1 wave = 1 softmax column u; 64 lanes x 3 t; shfl-only
// ===========================================================================
template<int A>
__device__ __forceinline__ float gather_val(const float* __restrict__ rs,
                                            int t, int u)
{
  constexpr int K = 2 * A + 1;
  float val = 0.f;
#pragma unroll
  for (int j = 0; j < K; ++j) {
    int tp = t + j - A;
    int d = tp - u;
    if (tp >= 0 && tp < 192 && d <= A && d >= -A) val += rs[j * 192 + tp];
  }
  return val;
}

__device__ __forceinline__ void abuild_body(
    const float* __restrict__ rbuf,
    const float* __restrict__ ba0, const float* __restrict__ ba1,
    const float* __restrict__ ba2, float* __restrict__ At,
    int ublk, int n, int tid)
{
  const int w = tid >> 6, lane = tid & 63;
  const int u = ublk * 4 + w;
  const int t0 = lane * 3;
  const float* r0 = rbuf + (size_t)(0 * 8 + n) * 11 * 192;
  const float* r1 = rbuf + (size_t)(1 * 8 + n) * 11 * 192;
  const float* r2 = rbuf + (size_t)(2 * 8 + n) * 11 * 192;
  float v0[3], v1[3], v2[3];
  const float b0 = ba0[0], b1 = ba1[0], b2 = ba2[0];
#pragma unroll
  for (int q = 0; q < 3; ++q) {
    v0[q] = b0 + gather_val<1>(r0, t0 + q, u);
    v1[q] = b1 + gather_val<3>(r1, t0 + q, u);
    v2[q] = b2 + gather_val<5>(r2, t0 + q, u);
  }
  float m0 = fmaxf(fmaxf(v0[0], v0[1]), v0[2]);
  float m1 = fmaxf(fmaxf(v1[0], v1[1]), v1[2]);
  float m2 = fmaxf(fmaxf(v2[0], v2[1]), v2[2]);
#pragma unroll
  for (int off = 32; off > 0; off >>= 1) {
    m0 = fmaxf(m0, __shfl_xor(m0, off));
    m1 = fmaxf(m1, __shfl_xor(m1, off));
    m2 = fmaxf(m2, __shfl_xor(m2, off));
  }
  float e0[3], e1[3], e2[3];
#pragma unroll
  for (int q = 0; q < 3; ++q) {
    e0[q] = __expf(v0[q] - m0);
    e1[q] = __expf(v1[q] - m1);
    e2[q] = __expf(v2[q] - m2);
  }
  float s0 = e0[0] + e0[1] + e0[2];
  float s1 = e1[0] + e1[1] + e1[2];
  float s2 = e2[0] + e2[1] + e2[2];
#pragma unroll
  for (int off = 32; off > 0; off >>= 1) {
    s0 += __shfl_xor(s0, off);
    s1 += __shfl_xor(s1, off);
    s2 += __shfl_xor(s2, off);
  }
  const float i0 = 1.f / s0, i1 = 1.f / s1, i2 = 1.f / s2;
  float* dst = &At[((size_t)n * 192 + u) * 192 + t0];
#pragma unroll
  for (int q = 0; q < 3; ++q)
    dst[q] = e0[q] * i0 + e1[q] * i1 + e2[q] * i2;
}

// ---- grouped conv (groups=32, K=3) + ReLU ---------------------------------
__device__ __forceinline__ void gconv_body(
    const float* __restrict__ hin, const float* __restrict__ w2,
    const float* __restrict__ b2, float* __restrict__ hout,
    int bx, int by, int n, int tid)
{
  const int t  = (tid & 63) + bx * 64;
  const int oc = (tid >> 6) + by * 4;
  const int g  = oc >> 3;
  float acc = b2[oc];
  for (int i = 0; i < 8; ++i) {
    const float* hrow = &hin[((size_t)n * 512 + g * 8 + i) * 192];
#pragma unroll
    for (int j = 0; j < 3; ++j) {
      int tt = t + j - 1;
      float hv = (tt >= 0 && tt < 192) ? hrow[tt] : 0.f;
      acc += w2[((size_t)oc * 8 + i) * 3 + j] * hv;
    }
  }
  hout[((size_t)n * 512 + 256 + oc) * 192 + t] = fmaxf(acc, 0.f);
}

// ---- At[n][u][t] -> Aout[n][t][u] ------------------------------------------
__device__ __forceinline__ void transpose_body(
    float* smem, const float* __restrict__ At, float* __restrict__ Aout,
    int bx, int by, int n, int tid)
{
  float (*tile)[33] = (float(*)[33])smem;
  const int xx = tid & 31, y = tid >> 5;
  for (int yy = y; yy < 32; yy += 8)
    tile[yy][xx] = At[((size_t)n * 192 + by * 32 + yy) * 192 + bx * 32 + xx];
  __syncthreads();
  for (int yy = y; yy < 32; yy += 8)
    Aout[((size_t)n * 192 + bx * 32 + yy) * 192 + by * 32 + xx] = tile[xx][yy];
}

// ===========================================================================
// Device-scope grid barrier (generation counter). Grid co-residency is
// guaranteed by __launch_bounds__(256,3) + LDS (3 x 34.8KB = 104KB < 160KB)
// and grid = 3 x 256 CU. Agent-scope acq/rel gives cross-XCD L2 visibility.
// ===========================================================================
__device__ __forceinline__ void grid_sync(unsigned* bar, unsigned nblk)
{
  __syncthreads();
  if (threadIdx.x == 0) {
    unsigned g = __hip_atomic_load(&bar[1], __ATOMIC_ACQUIRE,
                                   __HIP_MEMORY_SCOPE_AGENT);
    unsigned a = __hip_atomic_fetch_add(&bar[0], 1u, __ATOMIC_ACQ_REL,
                                        __HIP_MEMORY_SCOPE_AGENT);
    if (a == nblk - 1) {
      __hip_atomic_store(&bar[0], 0u, __ATOMIC_RELAXED,
                         __HIP_MEMORY_SCOPE_AGENT);
      __hip_atomic_store(&bar[1], g + 1u, __ATOMIC_RELEASE,
                         __HIP_MEMORY_SCOPE_AGENT);
    } else {
      while (__hip_atomic_load(&bar[1], __ATOMIC_ACQUIRE,
                               __HIP_MEMORY_SCOPE_AGENT) == g)
        __builtin_amdgcn_s_sleep(2);
    }
  }
  __syncthreads();
}

// ===========================================================================
// MEGA KERNEL: all 6 phases, 5 grid barriers, zero extra launches.
// Phase bodies identical to the 81.5us 6-launch version (R8).
// ===========================================================================
__global__ __launch_bounds__(256, 3) void mega_kernel(
    const float* __restrict__ x,
    const float* __restrict__ wp0, const float* __restrict__ bp0,
    const float* __restrict__ wk0, const float* __restrict__ bk0,
    const float* __restrict__ wa0, const float* __restrict__ ba0,
    const float* __restrict__ wp1, const float* __restrict__ bp1,
    const float* __restrict__ wk1, const float* __restrict__ bk1,
    const float* __restrict__ wa1, const float* __restrict__ ba1,
    const float* __restrict__ wp2, const float* __restrict__ bp2,
    const float* __restrict__ wk2, const float* __restrict__ bk2,
    const float* __restrict__ wa2, const float* __restrict__ ba2,
    const float* __restrict__ w1, const float* __restrict__ b1,
    const float* __restrict__ w2, const float* __restrict__ b2,
    const float* __restrict__ w3, const float* __restrict__ b3,
    float* __restrict__ hall, float* __restrict__ At, float* __restrict__ xs,
    float* __restrict__ rpart, float* __restrict__ rbuf,
    float* __restrict__ WXA, float* __restrict__ bpA, float* __restrict__ cka,
    float* __restrict__ partsA, unsigned* __restrict__ bar,
    float* __restrict__ out0, float* __restrict__ Aout)
{
  __shared__ __align__(16) float smem[8704];
  const int tid = threadIdx.x;
  const unsigned nb = gridDim.x;

  // ---- P1: gemm h1 (96) | foldA (48) | cka (1) = 145 ----
  for (unsigned u = blockIdx.x; u < 145; u += nb) {
    __syncthreads();
    if (u < 96) {
      gemm_body<false>(smem, w1, b1, x, hall, 512, 512, 512, 0,
                       (u % 3) * 64, ((u / 3) % 4) * 64, u / 12, tid);
    } else if (u < 144) {
      const int fbid = u - 96;
      const int s = fbid >> 4, sub = fbid & 15;
      const int chunk = sub >> 1, jg = sub & 1;
      if (s == 0) {
        if (jg == 0) foldA_body<3, 2>(wa0, wk0, partsA,          0, chunk, tid);
        else         foldA_body<3, 1>(wa0, wk0, partsA,          2, chunk, tid);
      } else if (s == 1) {
        if (jg == 0) foldA_body<7, 4>(wa1, wk1, partsA + 18432,  0, chunk, tid);
        else         foldA_body<7, 3>(wa1, wk1, partsA + 18432,  4, chunk, tid);
      } else {
        if (jg == 0) foldA_body<11, 6>(wa2, wk2, partsA + 118784, 0, chunk, tid);
        else         foldA_body<11, 5>(wa2, wk2, partsA + 118784, 6, chunk, tid);
      }
    } else {
      cka_body(wa0, bk0, wa1, bk1, wa2, bk2, cka, tid);
    }
  }
  grid_sync(bar, nb);

  // ---- P2: foldB (358) | gconv (1536) = 1894 ----
  for (unsigned u = blockIdx.x; u < 1894; u += nb) {
    __syncthreads();
    if (u < 18)
      foldB_body<3>(smem, partsA, wp0, bp0, WXA, bpA, u >> 1, u & 1, tid);
    else if (u < 116)
      foldB_body<7>(smem, partsA + 18432, wp1, bp1, WXA + 6144, bpA + 121,
                    (u - 18) >> 1, (u - 18) & 1, tid);
    else if (u < 358)
      foldB_body<11>(smem, partsA + 118784, wp2, bp2, WXA + 34816, bpA + 242,
                     (u - 116) >> 1, (u - 116) & 1, tid);
    else {
      const int gid = u - 358;
      gconv_body(hall, w2, b2, hall, gid % 3, (gid / 3) % 64, gid / 192, tid);
    }
  }
  grid_sync(bar, nb);

  // ---- P3: rcomp (768) | gemm w3 (96) = 864 ----
  for (unsigned u = blockIdx.x; u < 864; u += nb) {
    __syncthreads();
    if (u < 768) {
      const int cc = u % 32, n = (u / 32) % 8, s = u / 256;
      if (s == 0)      rcomp_body<1>(smem, x, WXA,         rpart,          cc, n, tid);
      else if (s == 1) rcomp_body<3>(smem, x, WXA + 6144,  rpart + 147456, cc, n, tid);
      else             rcomp_body<5>(smem, x, WXA + 34816, rpart + 491520, cc, n, tid);
    } else {
      const int gid = u - 768;
      gemm_body<false>(smem, w3, b3, hall + 256 * 192, xs, 256, 512, 256, 0,
                       (gid % 3) * 64, ((gid / 3) % 4) * 64, gid / 12, tid);
    }
  }
  grid_sync(bar, nb);

  // ---- P4: rreduce (168) ----
  for (unsigned u = blockIdx.x; u < 168; u += nb)
    rreduce_body(rpart, cka, bpA, rbuf, u % 8, u / 8, tid);
  grid_sync(bar, nb);

  // ---- P5: abuild (384) ----
  for (unsigned u = blockIdx.x; u < 384; u += nb)
    abuild_body(rbuf, ba0, ba1, ba2, At, u % 48, u / 48, tid);
  grid_sync(bar, nb);

  // ---- P6: final gemm (96) | transpose (288) = 384 ----
  for (unsigned u = blockIdx.x; u < 384; u += nb) {
    __syncthreads();
    if (u < 96) {
      gemm_body<true>(smem, xs, nullptr, At, out0, 192, 0, 256, 256 * 192,
                      (u % 3) * 64, ((u / 3) % 4) * 64, u / 12, tid);
    } else {
      const int gid = u - 96;
      transpose_body(smem, At, Aout, gid % 6, (gid / 6) % 6, gid / 36, tid);
    }
  }
}

// ===========================================================================
extern "C" void kernel_launch(void* const* d_in, const int* in_sizes, int n_in,
                              void* d_out, int out_size, void* d_ws, size_t ws_size,
                              hipStream_t stream)
{
  const float* x   = (const float*)d_in[0];
  const float* wp0 = (const float*)d_in[1];
  const float* bp0 = (const float*)d_in[2];
  const float* wk0 = (const float*)d_in[3];
  const float* bk0 = (const float*)d_in[4];
  const float* wa0 = (const float*)d_in[5];
  const float* ba0 = (const float*)d_in[6];
  const float* wp1 = (const float*)d_in[7];
  const float* bp1 = (const float*)d_in[8];
  const float* wk1 = (const float*)d_in[9];
  const float* bk1 = (const float*)d_in[10];
  const float* wa1 = (const float*)d_in[11];
  const float* ba1 = (const float*)d_in[12];
  const float* wp2 = (const float*)d_in[13];
  const float* bp2 = (const float*)d_in[14];
  const float* wk2 = (const float*)d_in[15];
  const float* bk2 = (const float*)d_in[16];
  const float* wa2 = (const float*)d_in[17];
  const float* ba2 = (const float*)d_in[18];
  const float* w1  = (const float*)d_in[19];
  const float* b1  = (const float*)d_in[20];
  const float* w2  = (const float*)d_in[21];
  const float* b2  = (const float*)d_in[22];
  const float* w3  = (const float*)d_in[23];
  const float* b3  = (const float*)d_in[24];

  float* ws     = (float*)d_ws;
  float* hall   = ws;                         // [8][512][192]        =   786,432
  float* At     = hall   + 786432;            // [8][192][192]        =   294,912
  float* xs     = At     + 294912;            // [8][256][192]        =   393,216
  float* rpart  = xs     + 393216;            // [8][32][3+7+11][192] = 1,032,192
  float* rbuf   = rpart  + 1032192;           // [3][8][11][192]      =    50,688
  float* WXA    = rbuf   + 50688;             // [512]*(12+56+132)    =   102,400
  float* bpA    = WXA    + 102400;            // [3][121]             =       384
  float* cka    = bpA    + 384;               // [3][11] (pad 64)     =        64
  float* partsA = cka    + 64;                // 8*(9+49+121)*256     =   366,592
  unsigned* bar = (unsigned*)(partsA + 366592);
  float* out0   = (float*)d_out;              // [8][256][192]
  float* Aout   = out0 + 8 * 256 * 192;       // [8][192][192]

  // barrier state must be zero every call (workspace is poisoned once)
  hipMemsetAsync(bar, 0, 2 * sizeof(unsigned), stream);

  mega_kernel<<<768, 256, 0, stream>>>(
      x,
      wp0, bp0, wk0, bk0, wa0, ba0,
      wp1, bp1, wk1, bk1, wa1, ba1,
      wp2, bp2, wk2, bk2, wa2, ba2,
      w1, b1, w2, b2, w3, b3,
      hall, At, xs, rpart, rbuf, WXA, bpA, cka, partsA, bar,
      out0, Aout);
}

// Round 11
// 1059.106 us; speedup vs baseline: 1.0356x; 1.0356x over previous
//
#include <hip/hip_runtime.h>

#define T_LEN 192

// ===========================================================================
// ---- tiled GEMM body: Y[n,o,t] = sum_c W[o,c]*X[c,t] + B[o] ---------------
// ===========================================================================
template<bool TRANSX>
__device__ __forceinline__ void gemm_body(
    float* smem,
    const float* __restrict__ W, const float* __restrict__ B,
    const float* __restrict__ X, float* __restrict__ Y,
    int cin, int cstr, int ostr, int wnstr,
    int t0, int o0, int n, int tid)
{
  float (*Ws)[68] = (float(*)[68])smem;             // [c][o]
  float (*Xs)[68] = (float(*)[68])(smem + 64 * 68); // [c][t]
  const int to = tid >> 4, tt = tid & 15;
  float acc[4][4] = {};

  for (int c0 = 0; c0 < cin; c0 += 64) {
    __syncthreads();
#pragma unroll
    for (int l = 0; l < 4; ++l) {
      int idx = l * 256 + tid;
      int rr = idx >> 4, c4 = idx & 15;
      float4 wv = *reinterpret_cast<const float4*>(
          &W[(size_t)n * wnstr + (size_t)(o0 + rr) * cin + c0 + c4 * 4]);
      Ws[c4 * 4 + 0][rr] = wv.x; Ws[c4 * 4 + 1][rr] = wv.y;
      Ws[c4 * 4 + 2][rr] = wv.z; Ws[c4 * 4 + 3][rr] = wv.w;
      if (!TRANSX) {
        float4 xv = *reinterpret_cast<const float4*>(
            &X[((size_t)n * cstr + c0 + rr) * T_LEN + t0 + c4 * 4]);
        *reinterpret_cast<float4*>(&Xs[rr][c4 * 4]) = xv;
      } else {
        float4 xv = *reinterpret_cast<const float4*>(
            &X[((size_t)n * 192 + t0 + rr) * 192 + c0 + c4 * 4]);
        Xs[c4 * 4 + 0][rr] = xv.x; Xs[c4 * 4 + 1][rr] = xv.y;
        Xs[c4 * 4 + 2][rr] = xv.z; Xs[c4 * 4 + 3][rr] = xv.w;
      }
    }
    __syncthreads();
#pragma unroll
    for (int kk = 0; kk < 64; ++kk) {
      float4 a = *reinterpret_cast<const float4*>(&Ws[kk][to * 4]);
      float4 b = *reinterpret_cast<const float4*>(&Xs[kk][tt * 4]);
      acc[0][0] += a.x * b.x; acc[0][1] += a.x * b.y; acc[0][2] += a.x * b.z; acc[0][3] += a.x * b.w;
      acc[1][0] += a.y * b.x; acc[1][1] += a.y * b.y; acc[1][2] += a.y * b.z; acc[1][3] += a.y * b.w;
      acc[2][0] += a.z * b.x; acc[2][1] += a.z * b.y; acc[2][2] += a.z * b.z; acc[2][3] += a.z * b.w;
      acc[3][0] += a.w * b.x; acc[3][1] += a.w * b.y; acc[3][2] += a.w * b.z; acc[3][3] += a.w * b.w;
    }
  }
#pragma unroll
  for (int i = 0; i < 4; ++i) {
    float bi = B ? B[o0 + to * 4 + i] : 0.f;
    float4 v = make_float4(acc[i][0] + bi, acc[i][1] + bi, acc[i][2] + bi, acc[i][3] + bi);
    *reinterpret_cast<float4*>(
        &Y[((size_t)n * ostr + o0 + to * 4 + i) * T_LEN + t0 + tt * 4]) = v;
  }
}

// ===========================================================================
// foldA: parts[chunk][j*K+i][c'] = sum_{c in 16-chunk} wa[c,j]*wk[c,c',i]
// ===========================================================================
template<int K, int JN>
__device__ __forceinline__ void foldA_body(
    const float* __restrict__ wa, const float* __restrict__ wk,
    float* __restrict__ parts, int j0, int chunk, int tid)
{
  float acc[JN][K];
#pragma unroll
  for (int jj = 0; jj < JN; ++jj)
#pragma unroll
    for (int i = 0; i < K; ++i) acc[jj][i] = 0.f;

  const int c0 = chunk * 16;
  for (int c = c0; c < c0 + 16; ++c) {
    const float* base = &wk[((size_t)c * 256 + tid) * K];
    float v[K];
#pragma unroll
    for (int i = 0; i < K; ++i) v[i] = base[i];
    float w[JN];
#pragma unroll
    for (int jj = 0; jj < JN; ++jj) w[jj] = wa[c * K + j0 + jj];
#pragma unroll
    for (int jj = 0; jj < JN; ++jj)
#pragma unroll
      for (int i = 0; i < K; ++i) acc[jj][i] += w[jj] * v[i];
  }
#pragma unroll
  for (int jj = 0; jj < JN; ++jj)
#pragma unroll
    for (int i = 0; i < K; ++i)
      parts[((size_t)chunk * K * K + (j0 + jj) * K + i) * 256 + tid] = acc[jj][i];
}

// ---- cka[s,j] = sum_c wa[c,j]*bk[c] ---------------------------------------
__device__ __forceinline__ void cka_body(
    const float* __restrict__ wa0, const float* __restrict__ bk0,
    const float* __restrict__ wa1, const float* __restrict__ bk1,
    const float* __restrict__ wa2, const float* __restrict__ bk2,
    float* __restrict__ cka, int tid)
{
  if (tid >= 21) return;
  int s, j, K; const float *wa, *bk;
  if (tid < 3)       { s = 0; j = tid;      K = 3;  wa = wa0; bk = bk0; }
  else if (tid < 10) { s = 1; j = tid - 3;  K = 7;  wa = wa1; bk = bk1; }
  else               { s = 2; j = tid - 10; K = 11; wa = wa2; bk = bk2; }
  float acc = 0.f;
  for (int c = 0; c < 128; ++c) acc += wa[c * K + j] * bk[c];
  cka[s * 11 + j] = acc;
}

// ===========================================================================
// foldB: stage chunk-summed WKA row in LDS, then coalesced wp GEMV.
// half==0 block also computes bpA[ji] via LDS dot.
// ===========================================================================
template<int K>
__device__ __forceinline__ void foldB_body(
    float* lds, const float* __restrict__ parts, const float* __restrict__ wp,
    const float* __restrict__ bp, float* __restrict__ wxas,
    float* __restrict__ bpA_s, int ji, int half, int tid)
{
  constexpr int KP = (K + 3) & ~3;
  constexpr int K2 = K * K;
  float s = 0.f;
#pragma unroll
  for (int ch = 0; ch < 8; ++ch)
    s += parts[((size_t)(ch * K2 + ji)) * 256 + tid];
  lds[tid] = s;
  __syncthreads();

  const int cin = half * 256 + tid;
  float acc = 0.f;
  for (int c = 0; c < 256; ++c)
    acc += lds[c] * wp[(size_t)c * 512 + cin];
  const int j = ji / K, i = ji - j * K;
  wxas[(size_t)cin * K * KP + i * KP + j] = acc;

  if (half == 0 && tid == 0) {
    float b = 0.f;
    for (int c = 0; c < 256; ++c) b += lds[c] * bp[c];
    bpA_s[j * 11 + i] = b;
  }
}

// ===========================================================================
// rcomp: rpart[n,cc,j,t] = sum_{16ch,i} WXA[c,i,j]*xpad[n,c,t+i-A]
// ===========================================================================
template<int A>
__device__ __forceinline__ void rcomp_body(
    float* smem, const float* __restrict__ x, const float* __restrict__ WXAs,
    float* __restrict__ rps, int cc, int n, int tid)
{
  constexpr int K  = 2 * A + 1;
  constexpr int KP = (K + 3) & ~3;
  constexpr int WH = 192 + 2 * A;
  constexpr int WS = 204;
  float* Xs = smem;               // 16 x 204
  float* Wl = smem + 16 * WS;     // 16 x K x KP
  const int c0 = cc * 16;

  for (int idx = tid; idx < 16 * WH; idx += 256) {
    int c = idx / WH, p = idx - c * WH;
    int tau = p - A;
    Xs[c * WS + p] = (tau >= 0 && tau < 192)
        ? x[((size_t)n * 512 + c0 + c) * 192 + tau] : 0.f;
  }
  {
    const float4* wg = reinterpret_cast<const float4*>(WXAs + (size_t)c0 * K * KP);
    float4* wl = reinterpret_cast<float4*>(Wl);
    for (int idx = tid; idx < 16 * K * KP / 4; idx += 256) wl[idx] = wg[idx];
  }
  __syncthreads();

  const int w = tid >> 6, lane = tid & 63;
  const int csub = lane >> 4, tpos = lane & 15;
  const int tb = w * 48 + tpos * 3;

  float acc[K][3];
#pragma unroll
  for (int j = 0; j < K; ++j) { acc[j][0] = 0.f; acc[j][1] = 0.f; acc[j][2] = 0.f; }

#pragma unroll
  for (int c = 0; c < 4; ++c) {
    const int ch = csub * 4 + c;
    float win[K + 2];
#pragma unroll
    for (int p = 0; p < K + 2; ++p) win[p] = Xs[ch * WS + tb + p];
    const float* wr = &Wl[ch * K * KP];
#pragma unroll
    for (int i = 0; i < K; ++i) {
#pragma unroll
      for (int j = 0; j < K; ++j) {
        float wv = wr[i * KP + j];
        acc[j][0] += wv * win[i + 0];
        acc[j][1] += wv * win[i + 1];
        acc[j][2] += wv * win[i + 2];
      }
    }
  }
#pragma unroll
  for (int j = 0; j < K; ++j) {
#pragma unroll
    for (int q = 0; q < 3; ++q) {
      float v = acc[j][q];
      v += __shfl_xor(v, 16);
      v += __shfl_xor(v, 32);
      acc[j][q] = v;
    }
  }
  if (csub == 0) {
#pragma unroll
    for (int j = 0; j < K; ++j) {
      float* dst = &rps[(((size_t)n * 32 + cc) * K + j) * 192 + tb];
      dst[0] = acc[j][0]; dst[1] = acc[j][1]; dst[2] = acc[j][2];
    }
  }
}

// ---- rreduce: rbuf[s,n,j,t] = sum_cc rpart + cka + boundary bp term -------
__device__ __forceinline__ void rreduce_body(
    const float* __restrict__ rpart, const float* __restrict__ cka,
    const float* __restrict__ bpA, float* __restrict__ rbuf,
    int n, int sj, int t)
{
  if (t >= 192) return;
  const int s = sj < 3 ? 0 : sj < 10 ? 1 : 2;
  const int j = sj < 3 ? sj : sj < 10 ? sj - 3 : sj - 10;
  const int A = (s == 0) ? 1 : (s == 1) ? 3 : 5;
  const int K = 2 * A + 1;
  const int roff = (s == 0) ? 0 : (s == 1) ? 147456 : 491520;
  const float* rp = rpart + roff;
  float acc = cka[s * 11 + j];
#pragma unroll 8
  for (int cc = 0; cc < 32; ++cc)
    acc += rp[(((size_t)n * 32 + cc) * K + j) * 192 + t];
  for (int i = 0; i < K; ++i) {
    int tau = t + i - A;
    if (tau >= 0 && tau < 192) acc += bpA[s * 121 + j * 11 + i];
  }
  rbuf[((size_t)(s * 8 + n) * 11 + j) * 192 + t] = acc;
}

// ===========================================================================
// abuild: 1 wave = 1 softmax column u; 64 lanes x 3 t; shfl-only
// ===========================================================================
template<int A>
__device__ __forceinline__ float gather_val(const float* __restrict__ rs,
                                            int t, int u)
{
  constexpr int K = 2 * A + 1;
  float val = 0.f;
#pragma unroll
  for (int j = 0; j < K; ++j) {
    int tp = t + j - A;
    int d = tp - u;
    if (tp >= 0 && tp < 192 && d <= A && d >= -A) val += rs[j * 192 + tp];
  }
  return val;
}

__device__ __forceinline__ void abuild_body(
    const float* __restrict__ rbuf,
    const float* __restrict__ ba0, const float* __restrict__ ba1,
    const float* __restrict__ ba2, float* __restrict__ At,
    int ublk, int n, int tid)
{
  const int w = tid >> 6, lane = tid & 63;
  const int u = ublk * 4 + w;
  const int t0 = lane * 3;
  const float* r0 = rbuf + (size_t)(0 * 8 + n) * 11 * 192;
  const float* r1 = rbuf + (size_t)(1 * 8 + n) * 11 * 192;
  const float* r2 = rbuf + (size_t)(2 * 8 + n) * 11 * 192;
  float v0[3], v1[3], v2[3];
  const float b0 = ba0[0], b1 = ba1[0], b2 = ba2[0];
#pragma unroll
  for (int q = 0; q < 3; ++q) {
    v0[q] = b0 + gather_val<1>(r0, t0 + q, u);
    v1[q] = b1 + gather_val<3>(r1, t0 + q, u);
    v2[q] = b2 + gather_val<5>(r2, t0 + q, u);
  }
  float m0 = fmaxf(fmaxf(v0[0], v0[1]), v0[2]);
  float m1 = fmaxf(fmaxf(v1[0], v1[1]), v1[2]);
  float m2 = fmaxf(fmaxf(v2[0], v2[1]), v2[2]);
#pragma unroll
  for (int off = 32; off > 0; off >>= 1) {
    m0 = fmaxf(m0, __shfl_xor(m0, off));
    m1 = fmaxf(m1, __shfl_xor(m1, off));
    m2 = fmaxf(m2, __shfl_xor(m2, off));
  }
  float e0[3], e1[3], e2[3];
#pragma unroll
  for (int q = 0; q < 3; ++q) {
    e0[q] = __expf(v0[q] - m0);
    e1[q] = __expf(v1[q] - m1);
    e2[q] = __expf(v2[q] - m2);
  }
  float s0 = e0[0] + e0[1] + e0[2];
  float s1 = e1[0] + e1[1] + e1[2];
  float s2 = e2[0] + e2[1] + e2[2];
#pragma unroll
  for (int off = 32; off > 0; off >>= 1) {
    s0 += __shfl_xor(s0, off);
    s1 += __shfl_xor(s1, off);
    s2 += __shfl_xor(s2, off);
  }
  const float i0 = 1.f / s0, i1 = 1.f / s1, i2 = 1.f / s2;
  float* dst = &At[((size_t)n * 192 + u) * 192 + t0];
#pragma unroll
  for (int q = 0; q < 3; ++q)
    dst[q] = e0[q] * i0 + e1[q] * i1 + e2[q] * i2;
}

// ---- grouped conv (groups=32, K=3) + ReLU ---------------------------------
__device__ __forceinline__ void gconv_body(
    const float* __restrict__ hin, const float* __restrict__ w2,
    const float* __restrict__ b2, float* __restrict__ hout,
    int bx, int by, int n, int tid)
{
  const int t  = (tid & 63) + bx * 64;
  const int oc = (tid >> 6) + by * 4;
  const int g  = oc >> 3;
  float acc = b2[oc];
  for (int i = 0; i < 8; ++i) {
    const float* hrow = &hin[((size_t)n * 512 + g * 8 + i) * 192];
#pragma unroll
    for (int j = 0; j < 3; ++j) {
      int tt = t + j - 1;
      float hv = (tt >= 0 && tt < 192) ? hrow[tt] : 0.f;
      acc += w2[((size_t)oc * 8 + i) * 3 + j] * hv;
    }
  }
  hout[((size_t)n * 512 + 256 + oc) * 192 + t] = fmaxf(acc, 0.f);
}

// ---- At[n][u][t] -> Aout[n][t][u] ------------------------------------------
__device__ __forceinline__ void transpose_body(
    float* smem, const float* __restrict__ At, float* __restrict__ Aout,
    int bx, int by, int n, int tid)
{
  float (*tile)[33] = (float(*)[33])smem;
  const int xx = tid & 31, y = tid >> 5;
  for (int yy = y; yy < 32; yy += 8)
    tile[yy][xx] = At[((size_t)n * 192 + by * 32 + yy) * 192 + bx * 32 + xx];
  __syncthreads();
  for (int yy = y; yy < 32; yy += 8)
    Aout[((size_t)n * 192 + bx * 32 + yy) * 192 + by * 32 + xx] = tile[xx][yy];
}

// ===========================================================================
// Sharded two-level grid barrier. 768 blocks = 8 groups x 96 (group =
// blockIdx&7, matching XCD round-robin heuristic -> polls stay L2-local).
// Counters/release words on separate 128B lines; s_sleep backoff.
// R10's single-line version collapsed (40MB of polling fetches, ~200us/bar).
// ===========================================================================
#define NBLK 768u
#define GSZ  96u

__device__ __forceinline__ void grid_sync(unsigned* bar)
{
  __syncthreads();
  if (threadIdx.x == 0) {
    const unsigned g = blockIdx.x & 7u;
    unsigned* gcnt = bar + g * 32;         // group arrival counter
    unsigned* ggen = bar + 256 + g * 32;   // group release word
    unsigned* mcnt = bar + 512;            // master counter
    unsigned* mgen = bar + 544;            // master release word
    const unsigned gen = __hip_atomic_load(ggen, __ATOMIC_ACQUIRE,
                                           __HIP_MEMORY_SCOPE_AGENT);
    const unsigned a = __hip_atomic_fetch_add(gcnt, 1u, __ATOMIC_ACQ_REL,
                                              __HIP_MEMORY_SCOPE_AGENT);
    if (a == GSZ - 1u) {                   // last in group
      __hip_atomic_store(gcnt, 0u, __ATOMIC_RELAXED, __HIP_MEMORY_SCOPE_AGENT);
      const unsigned m = __hip_atomic_fetch_add(mcnt, 1u, __ATOMIC_ACQ_REL,
                                                __HIP_MEMORY_SCOPE_AGENT);
      if (m == 7u) {                       // last group overall
        __hip_atomic_store(mcnt, 0u, __ATOMIC_RELAXED,
                           __HIP_MEMORY_SCOPE_AGENT);
        __hip_atomic_store(mgen, gen + 1u, __ATOMIC_RELEASE,
                           __HIP_MEMORY_SCOPE_AGENT);
      } else {
        while (__hip_atomic_load(mgen, __ATOMIC_ACQUIRE,
                                 __HIP_MEMORY_SCOPE_AGENT) == gen)
          __builtin_amdgcn_s_sleep(8);
      }
      __hip_atomic_store(ggen, gen + 1u, __ATOMIC_RELEASE,
                         __HIP_MEMORY_SCOPE_AGENT);
    } else {
      while (__hip_atomic_load(ggen, __ATOMIC_ACQUIRE,
                               __HIP_MEMORY_SCOPE_AGENT) == gen)
        __builtin_amdgcn_s_sleep(8);
    }
  }
  __syncthreads();
}

// ===========================================================================
// MEGA KERNEL v2: all 6 phases, 5 sharded grid barriers.
// Phase bodies identical to the 81.5us 6-launch version (R8).
// ===========================================================================
__global__ __launch_bounds__(256, 3) void mega_kernel(
    const float* __restrict__ x,
    const float* __restrict__ wp0, const float* __restrict__ bp0,
    const float* __restrict__ wk0, const float* __restrict__ bk0,
    const float* __restrict__ wa0, const float* __restrict__ ba0,
    const float* __restrict__ wp1, const float* __restrict__ bp1,
    const float* __restrict__ wk1, const float* __restrict__ bk1,
    const float* __restrict__ wa1, const float* __restrict__ ba1,
    const float* __restrict__ wp2, const float* __restrict__ bp2,
    const float* __restrict__ wk2, const float* __restrict__ bk2,
    const float* __restrict__ wa2, const float* __restrict__ ba2,
    const float* __restrict__ w1, const float* __restrict__ b1,
    const float* __restrict__ w2, const float* __restrict__ b2,
    const float* __restrict__ w3, const float* __restrict__ b3,
    float* __restrict__ hall, float* __restrict__ At, float* __restrict__ xs,
    float* __restrict__ rpart, float* __restrict__ rbuf,
    float* __restrict__ WXA, float* __restrict__ bpA, float* __restrict__ cka,
    float* __restrict__ partsA, unsigned* __restrict__ bar,
    float* __restrict__ out0, float* __restrict__ Aout)
{
  __shared__ __align__(16) float smem[8704];
  const int tid = threadIdx.x;
  const unsigned nb = gridDim.x;

  // ---- P1: gemm h1 (96) | foldA (48) | cka (1) = 145 ----
  for (unsigned u = blockIdx.x; u < 145; u += nb) {
    __syncthreads();
    if (u < 96) {
      gemm_body<false>(smem, w1, b1, x, hall, 512, 512, 512, 0,
                       (u % 3) * 64, ((u / 3) % 4) * 64, u / 12, tid);
    } else if (u < 144) {
      const int fbid = u - 96;
      const int s = fbid >> 4, sub = fbid & 15;
      const int chunk = sub >> 1, jg = sub & 1;
      if (s == 0) {
        if (jg == 0) foldA_body<3, 2>(wa0, wk0, partsA,          0, chunk, tid);
        else         foldA_body<3, 1>(wa0, wk0, partsA,          2, chunk, tid);
      } else if (s == 1) {
        if (jg == 0) foldA_body<7, 4>(wa1, wk1, partsA + 18432,  0, chunk, tid);
        else         foldA_body<7, 3>(wa1, wk1, partsA + 18432,  4, chunk, tid);
      } else {
        if (jg == 0) foldA_body<11, 6>(wa2, wk2, partsA + 118784, 0, chunk, tid);
        else         foldA_body<11, 5>(wa2, wk2, partsA + 118784, 6, chunk, tid);
      }
    } else {
      cka_body(wa0, bk0, wa1, bk1, wa2, bk2, cka, tid);
    }
  }
  grid_sync(bar);

  // ---- P2: foldB (358) | gconv (1536) = 1894 ----
  for (unsigned u = blockIdx.x; u < 1894; u += nb) {
    __syncthreads();
    if (u < 18)
      foldB_body<3>(smem, partsA, wp0, bp0, WXA, bpA, u >> 1, u & 1, tid);
    else if (u < 116)
      foldB_body<7>(smem, partsA + 18432, wp1, bp1, WXA + 6144, bpA + 121,
                    (u - 18) >> 1, (u - 18) & 1, tid);
    else if (u < 358)
      foldB_body<11>(smem, partsA + 118784, wp2, bp2, WXA + 34816, bpA + 242,
                     (u - 116) >> 1, (u - 116) & 1, tid);
    else {
      const int gid = u - 358;
      gconv_body(hall, w2, b2, hall, gid % 3, (gid / 3) % 64, gid / 192, tid);
    }
  }
  grid_sync(bar);

  // ---- P3: rcomp (768) | gemm w3 (96) = 864 ----
  for (unsigned u = blockIdx.x; u < 864; u += nb) {
    __syncthreads();
    if (u < 768) {
      const int cc = u % 32, n = (u / 32) % 8, s = u / 256;
      if (s == 0)      rcomp_body<1>(smem, x, WXA,         rpart,          cc, n, tid);
      else if (s == 1) rcomp_body<3>(smem, x, WXA + 6144,  rpart + 147456, cc, n, tid);
      else             rcomp_body<5>(smem, x, WXA + 34816, rpart + 491520, cc, n, tid);
    } else {
      const int gid = u - 768;
      gemm_body<false>(smem, w3, b3, hall + 256 * 192, xs, 256, 512, 256, 0,
                       (gid % 3) * 64, ((gid / 3) % 4) * 64, gid / 12, tid);
    }
  }
  grid_sync(bar);

  // ---- P4: rreduce (168) ----
  for (unsigned u = blockIdx.x; u < 168; u += nb)
    rreduce_body(rpart, cka, bpA, rbuf, u % 8, u / 8, tid);
  grid_sync(bar);

  // ---- P5: abuild (384) ----
  for (unsigned u = blockIdx.x; u < 384; u += nb)
    abuild_body(rbuf, ba0, ba1, ba2, At, u % 48, u / 48, tid);
  grid_sync(bar);

  // ---- P6: final gemm (96) | transpose (288) = 384 ----
  for (unsigned u = blockIdx.x; u < 384; u += nb) {
    __syncthreads();
    if (u < 96) {
      gemm_body<true>(smem, xs, nullptr, At, out0, 192, 0, 256, 256 * 192,
                      (u % 3) * 64, ((u / 3) % 4) * 64, u / 12, tid);
    } else {
      const int gid = u - 96;
      transpose_body(smem, At, Aout, gid % 6, (gid / 6) % 6, gid / 36, tid);
    }
  }
}

// ===========================================================================
extern "C" void kernel_launch(void* const* d_in, const int* in_sizes, int n_in,
                              void* d_out, int out_size, void* d_ws, size_t ws_size,
                              hipStream_t stream)
{
  const float* x   = (const float*)d_in[0];
  const float* wp0 = (const float*)d_in[1];
  const float* bp0 = (const float*)d_in[2];
  const float* wk0 = (const float*)d_in[3];
  const float* bk0 = (const float*)d_in[4];
  const float* wa0 = (const float*)d_in[5];
  const float* ba0 = (const float*)d_in[6];
  const float* wp1 = (const float*)d_in[7];
  const float* bp1 = (const float*)d_in[8];
  const float* wk1 = (const float*)d_in[9];
  const float* bk1 = (const float*)d_in[10];
  const float* wa1 = (const float*)d_in[11];
  const float* ba1 = (const float*)d_in[12];
  const float* wp2 = (const float*)d_in[13];
  const float* bp2 = (const float*)d_in[14];
  const float* wk2 = (const float*)d_in[15];
  const float* bk2 = (const float*)d_in[16];
  const float* wa2 = (const float*)d_in[17];
  const float* ba2 = (const float*)d_in[18];
  const float* w1  = (const float*)d_in[19];
  const float* b1  = (const float*)d_in[20];
  const float* w2  = (const float*)d_in[21];
  const float* b2  = (const float*)d_in[22];
  const float* w3  = (const float*)d_in[23];
  const float* b3  = (const float*)d_in[24];

  float* ws     = (float*)d_ws;
  float* hall   = ws;                         // [8][512][192]        =   786,432
  float* At     = hall   + 786432;            // [8][192][192]        =   294,912
  float* xs     = At     + 294912;            // [8][256][192]        =   393,216
  float* rpart  = xs     + 393216;            // [8][32][3+7+11][192] = 1,032,192
  float* rbuf   = rpart  + 1032192;           // [3][8][11][192]      =    50,688
  float* WXA    = rbuf   + 50688;             // [512]*(12+56+132)    =   102,400
  float* bpA    = WXA    + 102400;            // [3][121]             =       384
  float* cka    = bpA    + 384;               // [3][11] (pad 64)     =        64
  float* partsA = cka    + 64;                // 8*(9+49+121)*256     =   366,592
  unsigned* bar = (unsigned*)(partsA + 366592);  // 1024 u32 (sharded barrier)
  float* out0   = (float*)d_out;              // [8][256][192]
  float* Aout   = out0 + 8 * 256 * 192;       // [8][192][192]

  // barrier state must be zero every call (workspace is poisoned once)
  hipMemsetAsync(bar, 0, 1024 * sizeof(unsigned), stream);

  mega_kernel<<<NBLK, 256, 0, stream>>>(
      x,
      wp0, bp0, wk0, bk0, wa0, ba0,
      wp1, bp1, wk1, bk1, wa1, ba1,
      wp2, bp2, wk2, bk2, wa2, ba2,
      w1, b1, w2, b2, w3, b3,
      hall, At, xs, rpart, rbuf, WXA, bpA, cka, partsA, bar,
      out0, Aout);
}

// Round 12
// 90.346 us; speedup vs baseline: 12.1402x; 11.7228x over previous
//
#include <hip/hip_runtime.h>

#define T_LEN 192

// ===========================================================================
// ---- tiled GEMM body: Y[n,o,t] = sum_c W[o,c]*X[c,t] + B[o] ---------------
// TRANSX=false: X[c,t] = Xg[(n*cstr + c)*192 + t]
// TRANSX=true : X[c,u] = Xg[(n*192 + u)*192 + c]   (At layout, transposed)
// ===========================================================================
template<bool TRANSX>
__device__ __forceinline__ void gemm_body(
    float* smem,
    const float* __restrict__ W, const float* __restrict__ B,
    const float* __restrict__ X, float* __restrict__ Y,
    int cin, int cstr, int ostr, int wnstr,
    int t0, int o0, int n, int tid)
{
  float (*Ws)[68] = (float(*)[68])smem;             // [c][o]
  float (*Xs)[68] = (float(*)[68])(smem + 64 * 68); // [c][t]
  const int to = tid >> 4, tt = tid & 15;
  float acc[4][4] = {};

  for (int c0 = 0; c0 < cin; c0 += 64) {
    __syncthreads();
#pragma unroll
    for (int l = 0; l < 4; ++l) {
      int idx = l * 256 + tid;
      int rr = idx >> 4, c4 = idx & 15;
      float4 wv = *reinterpret_cast<const float4*>(
          &W[(size_t)n * wnstr + (size_t)(o0 + rr) * cin + c0 + c4 * 4]);
      Ws[c4 * 4 + 0][rr] = wv.x; Ws[c4 * 4 + 1][rr] = wv.y;
      Ws[c4 * 4 + 2][rr] = wv.z; Ws[c4 * 4 + 3][rr] = wv.w;
      if (!TRANSX) {
        float4 xv = *reinterpret_cast<const float4*>(
            &X[((size_t)n * cstr + c0 + rr) * T_LEN + t0 + c4 * 4]);
        *reinterpret_cast<float4*>(&Xs[rr][c4 * 4]) = xv;
      } else {
        float4 xv = *reinterpret_cast<const float4*>(
            &X[((size_t)n * 192 + t0 + rr) * 192 + c0 + c4 * 4]);
        Xs[c4 * 4 + 0][rr] = xv.x; Xs[c4 * 4 + 1][rr] = xv.y;
        Xs[c4 * 4 + 2][rr] = xv.z; Xs[c4 * 4 + 3][rr] = xv.w;
      }
    }
    __syncthreads();
#pragma unroll
    for (int kk = 0; kk < 64; ++kk) {
      float4 a = *reinterpret_cast<const float4*>(&Ws[kk][to * 4]);
      float4 b = *reinterpret_cast<const float4*>(&Xs[kk][tt * 4]);
      acc[0][0] += a.x * b.x; acc[0][1] += a.x * b.y; acc[0][2] += a.x * b.z; acc[0][3] += a.x * b.w;
      acc[1][0] += a.y * b.x; acc[1][1] += a.y * b.y; acc[1][2] += a.y * b.z; acc[1][3] += a.y * b.w;
      acc[2][0] += a.z * b.x; acc[2][1] += a.z * b.y; acc[2][2] += a.z * b.z; acc[2][3] += a.z * b.w;
      acc[3][0] += a.w * b.x; acc[3][1] += a.w * b.y; acc[3][2] += a.w * b.z; acc[3][3] += a.w * b.w;
    }
  }
#pragma unroll
  for (int i = 0; i < 4; ++i) {
    float bi = B ? B[o0 + to * 4 + i] : 0.f;
    float4 v = make_float4(acc[i][0] + bi, acc[i][1] + bi, acc[i][2] + bi, acc[i][3] + bi);
    *reinterpret_cast<float4*>(
        &Y[((size_t)n * ostr + o0 + to * 4 + i) * T_LEN + t0 + tt * 4]) = v;
  }
}

// ===========================================================================
// foldA: parts[ji][c'][chunk] = sum_{c in 16-chunk} wa[c,j]*wk[c,c',i]
// Barrier-free: thread = c' (256), block = (s, chunk of 16 c, j-group).
// Output layout [ji][256][8] so consumers sum 8 CONTIGUOUS floats.
// ===========================================================================
template<int K, int JN>
__device__ __forceinline__ void foldA_body(
    const float* __restrict__ wa, const float* __restrict__ wk,
    float* __restrict__ parts, int j0, int chunk, int tid)
{
  float acc[JN][K];
#pragma unroll
  for (int jj = 0; jj < JN; ++jj)
#pragma unroll
    for (int i = 0; i < K; ++i) acc[jj][i] = 0.f;

  const int c0 = chunk * 16;
  for (int c = c0; c < c0 + 16; ++c) {
    const float* base = &wk[((size_t)c * 256 + tid) * K];
    float v[K];
#pragma unroll
    for (int i = 0; i < K; ++i) v[i] = base[i];
    float w[JN];
#pragma unroll
    for (int jj = 0; jj < JN; ++jj) w[jj] = wa[c * K + j0 + jj];
#pragma unroll
    for (int jj = 0; jj < JN; ++jj)
#pragma unroll
      for (int i = 0; i < K; ++i) acc[jj][i] += w[jj] * v[i];
  }
#pragma unroll
  for (int jj = 0; jj < JN; ++jj)
#pragma unroll
    for (int i = 0; i < K; ++i)
      parts[((size_t)((j0 + jj) * K + i) * 256 + tid) * 8 + chunk] = acc[jj][i];
}

// ---- cka[s,j] = sum_c wa[c,j]*bk[c] ---------------------------------------
__device__ __forceinline__ void cka_body(
    const float* __restrict__ wa0, const float* __restrict__ bk0,
    const float* __restrict__ wa1, const float* __restrict__ bk1,
    const float* __restrict__ wa2, const float* __restrict__ bk2,
    float* __restrict__ cka, int tid)
{
  if (tid >= 21) return;
  int s, j, K; const float *wa, *bk;
  if (tid < 3)       { s = 0; j = tid;      K = 3;  wa = wa0; bk = bk0; }
  else if (tid < 10) { s = 1; j = tid - 3;  K = 7;  wa = wa1; bk = bk1; }
  else               { s = 2; j = tid - 10; K = 11; wa = wa2; bk = bk2; }
  float acc = 0.f;
  for (int c = 0; c < 128; ++c) acc += wa[c * K + j] * bk[c];
  cka[s * 11 + j] = acc;
}

// ===========================================================================
// rcompK: banded conv against h_s (256 ch per scale) using WKA directly:
// rpart[n,cc,j,t] = sum_{16ch c', i} WKA[j,i,c'] * h_pad[n, s*256+c', t+i-A]
// (h_s includes bias bp; zero-padded halo == reference conv padding.)
// Weight stage sums the 8 contiguous chunk-partials from foldA.
// 4 waves x 48 t; lane = csub(4) x tpos(16); 3 t per lane; shfl csub-reduce.
// ===========================================================================
template<int A>
__device__ __forceinline__ void rcompk_body(
    float* smem, const float* __restrict__ hs_s,
    const float* __restrict__ parts_s, float* __restrict__ rps,
    int cc, int n, int tid)
{
  constexpr int K  = 2 * A + 1;
  constexpr int KP = (K + 3) & ~3;
  constexpr int WH = 192 + 2 * A;
  constexpr int WS = 204;
  float* Xs = smem;               // 16 x 204
  float* Wl = smem + 16 * WS;     // 16 x K x KP
  const int c0 = cc * 16;

  // stage h rows (zero halo)
  for (int idx = tid; idx < 16 * WH; idx += 256) {
    int c = idx / WH, p = idx - c * WH;
    int tau = p - A;
    Xs[c * WS + p] = (tau >= 0 && tau < 192)
        ? hs_s[((size_t)n * 768 + c0 + c) * 192 + tau] : 0.f;
  }
  // stage weights: Wl[c][i][jp] = sum_{8 chunks} parts[ji][c0+c][ch]
  for (int idx = tid; idx < 16 * K * K; idx += 256) {
    int ji = idx >> 4, c = idx & 15;
    const float* p = &parts_s[((size_t)ji * 256 + c0 + c) * 8];
    float4 a = *reinterpret_cast<const float4*>(p);
    float4 b = *reinterpret_cast<const float4*>(p + 4);
    float wsum = (a.x + a.y + a.z + a.w) + (b.x + b.y + b.z + b.w);
    int j = ji / K, i = ji - j * K;
    Wl[c * K * KP + i * KP + j] = wsum;
  }
  __syncthreads();

  const int w = tid >> 6, lane = tid & 63;
  const int csub = lane >> 4, tpos = lane & 15;
  const int tb = w * 48 + tpos * 3;

  float acc[K][3];
#pragma unroll
  for (int j = 0; j < K; ++j) { acc[j][0] = 0.f; acc[j][1] = 0.f; acc[j][2] = 0.f; }

#pragma unroll
  for (int c = 0; c < 4; ++c) {
    const int ch = csub * 4 + c;
    float win[K + 2];
#pragma unroll
    for (int p = 0; p < K + 2; ++p) win[p] = Xs[ch * WS + tb + p];
    const float* wr = &Wl[ch * K * KP];
#pragma unroll
    for (int i = 0; i < K; ++i) {
#pragma unroll
      for (int j = 0; j < K; ++j) {
        float wv = wr[i * KP + j];
        acc[j][0] += wv * win[i + 0];
        acc[j][1] += wv * win[i + 1];
        acc[j][2] += wv * win[i + 2];
      }
    }
  }
#pragma unroll
  for (int j = 0; j < K; ++j) {
#pragma unroll
    for (int q = 0; q < 3; ++q) {
      float v = acc[j][q];
      v += __shfl_xor(v, 16);
      v += __shfl_xor(v, 32);
      acc[j][q] = v;
    }
  }
  if (csub == 0) {
#pragma unroll
    for (int j = 0; j < K; ++j) {
      float* dst = &rps[(((size_t)n * 16 + cc) * K + j) * 192 + tb];
      dst[0] = acc[j][0]; dst[1] = acc[j][1]; dst[2] = acc[j][2];
    }
  }
}

// ---- rreduce: rbuf[s,n,j,t] = cka[s,j] + sum_{16 cc} rpart ---------------
__device__ __forceinline__ void rreduce_body(
    const float* __restrict__ rpart, const float* __restrict__ cka,
    float* __restrict__ rbuf, int n, int sj, int t)
{
  if (t >= 192) return;
  const int s = sj < 3 ? 0 : sj < 10 ? 1 : 2;
  const int j = sj < 3 ? sj : sj < 10 ? sj - 3 : sj - 10;
  const int K = (s == 0) ? 3 : (s == 1) ? 7 : 11;
  const int roff = (s == 0) ? 0 : (s == 1) ? 73728 : 245760;
  const float* rp = rpart + roff;
  float acc = cka[s * 11 + j];
#pragma unroll 8
  for (int cc = 0; cc < 16; ++cc)
    acc += rp[(((size_t)n * 16 + cc) * K + j) * 192 + t];
  rbuf[((size_t)(s * 8 + n) * 11 + j) * 192 + t] = acc;
}

// ===========================================================================
// abuild: 1 wave = 1 softmax column u; 64 lanes x 3 t; shfl-only
// ===========================================================================
template<int A>
__device__ __forceinline__ float gather_val(const float* __restrict__ rs,
                                            int t, int u)
{
  constexpr int K = 2 * A + 1;
  float val = 0.f;
#pragma unroll
  for (int j = 0; j < K; ++j) {
    int tp = t + j - A;
    int d = tp - u;
    if (tp >= 0 && tp < 192 && d <= A && d >= -A) val += rs[j * 192 + tp];
  }
  return val;
}

__device__ __forceinline__ void abuild_body(
    const float* __restrict__ rbuf,
    const float* __restrict__ ba0, const float* __restrict__ ba1,
    const float* __restrict__ ba2, float* __restrict__ At,
    int ublk, int n, int tid)
{
  const int w = tid >> 6, lane = tid & 63;
  const int u = ublk * 4 + w;
  const int t0 = lane * 3;
  const float* r0 = rbuf + (size_t)(0 * 8 + n) * 11 * 192;
  const float* r1 = rbuf + (size_t)(1 * 8 + n) * 11 * 192;
  const float* r2 = rbuf + (size_t)(2 * 8 + n) * 11 * 192;
  float v0[3], v1[3], v2[3];
  const float b0 = ba0[0], b1 = ba1[0], b2 = ba2[0];
#pragma unroll
  for (int q = 0; q < 3; ++q) {
    v0[q] = b0 + gather_val<1>(r0, t0 + q, u);
    v1[q] = b1 + gather_val<3>(r1, t0 + q, u);
    v2[q] = b2 + gather_val<5>(r2, t0 + q, u);
  }
  float m0 = fmaxf(fmaxf(v0[0], v0[1]), v0[2]);
  float m1 = fmaxf(fmaxf(v1[0], v1[1]), v1[2]);
  float m2 = fmaxf(fmaxf(v2[0], v2[1]), v2[2]);
#pragma unroll
  for (int off = 32; off > 0; off >>= 1) {
    m0 = fmaxf(m0, __shfl_xor(m0, off));
    m1 = fmaxf(m1, __shfl_xor(m1, off));
    m2 = fmaxf(m2, __shfl_xor(m2, off));
  }
  float e0[3], e1[3], e2[3];
#pragma unroll
  for (int q = 0; q < 3; ++q) {
    e0[q] = __expf(v0[q] - m0);
    e1[q] = __expf(v1[q] - m1);
    e2[q] = __expf(v2[q] - m2);
  }
  float s0 = e0[0] + e0[1] + e0[2];
  float s1 = e1[0] + e1[1] + e1[2];
  float s2 = e2[0] + e2[1] + e2[2];
#pragma unroll
  for (int off = 32; off > 0; off >>= 1) {
    s0 += __shfl_xor(s0, off);
    s1 += __shfl_xor(s1, off);
    s2 += __shfl_xor(s2, off);
  }
  const float i0 = 1.f / s0, i1 = 1.f / s1, i2 = 1.f / s2;
  float* dst = &At[((size_t)n * 192 + u) * 192 + t0];
#pragma unroll
  for (int q = 0; q < 3; ++q)
    dst[q] = e0[q] * i0 + e1[q] * i1 + e2[q] * i2;
}

// ---- grouped conv (groups=32, K=3) + ReLU ---------------------------------
__device__ __forceinline__ void gconv_body(
    const float* __restrict__ hin, const float* __restrict__ w2,
    const float* __restrict__ b2, float* __restrict__ hout,
    int bx, int by, int n, int tid)
{
  const int t  = (tid & 63) + bx * 64;
  const int oc = (tid >> 6) + by * 4;
  const int g  = oc >> 3;
  float acc = b2[oc];
  for (int i = 0; i < 8; ++i) {
    const float* hrow = &hin[((size_t)n * 512 + g * 8 + i) * 192];
#pragma unroll
    for (int j = 0; j < 3; ++j) {
      int tt = t + j - 1;
      float hv = (tt >= 0 && tt < 192) ? hrow[tt] : 0.f;
      acc += w2[((size_t)oc * 8 + i) * 3 + j] * hv;
    }
  }
  hout[((size_t)n * 512 + 256 + oc) * 192 + t] = fmaxf(acc, 0.f);
}

// ---- At[n][u][t] -> Aout[n][t][u] ------------------------------------------
__device__ __forceinline__ void transpose_body(
    float* smem, const float* __restrict__ At, float* __restrict__ Aout,
    int bx, int by, int n, int tid)
{
  float (*tile)[33] = (float(*)[33])smem;
  const int xx = tid & 31, y = tid >> 5;
  for (int yy = y; yy < 32; yy += 8)
    tile[yy][xx] = At[((size_t)n * 192 + by * 32 + yy) * 192 + bx * 32 + xx];
  __syncthreads();
  for (int yy = y; yy < 32; yy += 8)
    Aout[((size_t)n * 192 + bx * 32 + yy) * 192 + by * 32 + xx] = tile[xx][yy];
}

// ===========================================================================
// P1: 4 projections h0|h1|h2 -> hs, h1main -> hall (384)  ||  foldA (48)
//     ||  cka (1)   = 433 blocks
// ===========================================================================
__global__ __launch_bounds__(256) void p1_kernel(
    const float* __restrict__ x,
    const float* __restrict__ wp0, const float* __restrict__ bp0,
    const float* __restrict__ wp1, const float* __restrict__ bp1,
    const float* __restrict__ wp2, const float* __restrict__ bp2,
    const float* __restrict__ w1, const float* __restrict__ b1,
    const float* __restrict__ wa0, const float* __restrict__ wk0,
    const float* __restrict__ bk0,
    const float* __restrict__ wa1, const float* __restrict__ wk1,
    const float* __restrict__ bk1,
    const float* __restrict__ wa2, const float* __restrict__ wk2,
    const float* __restrict__ bk2,
    float* __restrict__ hs, float* __restrict__ hall,
    float* __restrict__ partsA, float* __restrict__ cka)
{
  __shared__ __align__(16) float smem[8704];
  const int bid = blockIdx.x, tid = threadIdx.x;
  if (bid < 384) {
    const int proj = bid / 96, gid = bid % 96;
    const int tx = gid % 3, oy = (gid / 3) % 4, n = gid / 12;
    const float* W = proj == 0 ? wp0 : proj == 1 ? wp1 : proj == 2 ? wp2 : w1;
    const float* B = proj == 0 ? bp0 : proj == 1 ? bp1 : proj == 2 ? bp2 : b1;
    float* Y  = proj < 3 ? hs + (size_t)proj * 256 * 192 : hall;
    int ostr  = proj < 3 ? 768 : 512;
    gemm_body<false>(smem, W, B, x, Y, 512, 512, ostr, 0,
                     tx * 64, oy * 64, n, tid);
  } else if (bid < 432) {
    const int fbid = bid - 384;           // 0..47
    const int s = fbid >> 4, sub = fbid & 15;
    const int chunk = sub >> 1, jg = sub & 1;
    if (s == 0) {
      if (jg == 0) foldA_body<3, 2>(wa0, wk0, partsA,          0, chunk, tid);
      else         foldA_body<3, 1>(wa0, wk0, partsA,          2, chunk, tid);
    } else if (s == 1) {
      if (jg == 0) foldA_body<7, 4>(wa1, wk1, partsA + 18432,  0, chunk, tid);
      else         foldA_body<7, 3>(wa1, wk1, partsA + 18432,  4, chunk, tid);
    } else {
      if (jg == 0) foldA_body<11, 6>(wa2, wk2, partsA + 118784, 0, chunk, tid);
      else         foldA_body<11, 5>(wa2, wk2, partsA + 118784, 6, chunk, tid);
    }
  } else {
    cka_body(wa0, bk0, wa1, bk1, wa2, bk2, cka, tid);
  }
}

// ===========================================================================
// P2: rcompK (384: 16cc x 8n x 3s)  ||  gconv (1536)   = 1920 blocks
// ===========================================================================
__global__ __launch_bounds__(256) void p2_kernel(
    const float* __restrict__ hs, const float* __restrict__ partsA,
    float* __restrict__ rpart,
    const float* __restrict__ w2, const float* __restrict__ b2,
    float* __restrict__ hall)
{
  __shared__ __align__(16) float smem[5440];
  const int bid = blockIdx.x, tid = threadIdx.x;
  if (bid < 384) {
    const int cc = bid % 16, n = (bid / 16) % 8, s = bid / 128;
    if (s == 0)
      rcompk_body<1>(smem, hs,                 partsA,          rpart,          cc, n, tid);
    else if (s == 1)
      rcompk_body<3>(smem, hs + 256 * 192,     partsA + 18432,  rpart + 73728,  cc, n, tid);
    else
      rcompk_body<5>(smem, hs + 512 * 192,     partsA + 118784, rpart + 245760, cc, n, tid);
  } else {
    const int gid = bid - 384;
    gconv_body(hall, w2, b2, hall, gid % 3, (gid / 3) % 64, gid / 192, tid);
  }
}

// ===========================================================================
// P3: rreduce (168)  ||  gemm w3 (96)   = 264 blocks
// ===========================================================================
__global__ __launch_bounds__(256) void p3_kernel(
    const float* __restrict__ rpart, const float* __restrict__ cka,
    float* __restrict__ rbuf,
    const float* __restrict__ hall, const float* __restrict__ w3,
    const float* __restrict__ b3, float* __restrict__ xs)
{
  __shared__ __align__(16) float smem[8704];
  const int bid = blockIdx.x, tid = threadIdx.x;
  if (bid < 168) {
    rreduce_body(rpart, cka, rbuf, bid % 8, bid / 8, tid);
  } else {
    const int gid = bid - 168;
    const int tx = gid % 3, oy = (gid / 3) % 4, n = gid / 12;
    gemm_body<false>(smem, w3, b3, hall + 256 * 192, xs, 256, 512, 256, 0,
                     tx * 64, oy * 64, n, tid);
  }
}

// ===========================================================================
// P4: abuild (384)
// ===========================================================================
__global__ __launch_bounds__(256) void p4_kernel(
    const float* __restrict__ rbuf,
    const float* __restrict__ ba0, const float* __restrict__ ba1,
    const float* __restrict__ ba2, float* __restrict__ At)
{
  abuild_body(rbuf, ba0, ba1, ba2, At, blockIdx.x % 48, blockIdx.x / 48,
              threadIdx.x);
}

// ===========================================================================
// P5: out0 = xs@A (96, At read transposed)  ||  transpose (288)  = 384
// ===========================================================================
__global__ __launch_bounds__(256) void p5_kernel(
    const float* __restrict__ xs, const float* __restrict__ At,
    float* __restrict__ out0, float* __restrict__ Aout)
{
  __shared__ __align__(16) float smem[8704];
  const int bid = blockIdx.x, tid = threadIdx.x;
  if (bid < 96) {
    const int tx = bid % 3, oy = (bid / 3) % 4, n = bid / 12;
    gemm_body<true>(smem, xs, nullptr, At, out0, 192, 0, 256, 256 * 192,
                    tx * 64, oy * 64, n, tid);
  } else {
    const int gid = bid - 96;
    transpose_body(smem, At, Aout, gid % 6, (gid / 6) % 6, gid / 36, tid);
  }
}

// ===========================================================================
extern "C" void kernel_launch(void* const* d_in, const int* in_sizes, int n_in,
                              void* d_out, int out_size, void* d_ws, size_t ws_size,
                              hipStream_t stream)
{
  const float* x   = (const float*)d_in[0];
  const float* wp0 = (const float*)d_in[1];
  const float* bp0 = (const float*)d_in[2];
  const float* wk0 = (const float*)d_in[3];
  const float* bk0 = (const float*)d_in[4];
  const float* wa0 = (const float*)d_in[5];
  const float* ba0 = (const float*)d_in[6];
  const float* wp1 = (const float*)d_in[7];
  const float* bp1 = (const float*)d_in[8];
  const float* wk1 = (const float*)d_in[9];
  const float* bk1 = (const float*)d_in[10];
  const float* wa1 = (const float*)d_in[11];
  const float* ba1 = (const float*)d_in[12];
  const float* wp2 = (const float*)d_in[13];
  const float* bp2 = (const float*)d_in[14];
  const float* wk2 = (const float*)d_in[15];
  const float* bk2 = (const float*)d_in[16];
  const float* wa2 = (const float*)d_in[17];
  const float* ba2 = (const float*)d_in[18];
  const float* w1  = (const float*)d_in[19];
  const float* b1  = (const float*)d_in[20];
  const float* w2  = (const float*)d_in[21];
  const float* b2  = (const float*)d_in[22];
  const float* w3  = (const float*)d_in[23];
  const float* b3  = (const float*)d_in[24];

  float* ws     = (float*)d_ws;
  float* hall   = ws;                         // [8][512][192]      =   786,432
  float* hs     = hall   + 786432;            // [8][768][192]      = 1,179,648
  float* At     = hs     + 1179648;           // [8][192][192]      =   294,912
  float* xs     = At     + 294912;            // [8][256][192]      =   393,216
  float* rpart  = xs     + 393216;            // per-scale 16-chunk =   516,096
  float* rbuf   = rpart  + 516096;            // [3][8][11][192]    =    50,688
  float* cka    = rbuf   + 50688;             // [3][11] (pad 64)   =        64
  float* partsA = cka    + 64;                // (9+49+121)*256*8   =   366,592
  float* out0   = (float*)d_out;              // [8][256][192]
  float* Aout   = out0 + 8 * 256 * 192;       // [8][192][192]

  // P1: h0|h1|h2 -> hs, h1main -> hall  ||  foldA -> partsA  ||  cka
  p1_kernel<<<433, 256, 0, stream>>>(
      x, wp0, bp0, wp1, bp1, wp2, bp2, w1, b1,
      wa0, wk0, bk0, wa1, wk1, bk1, wa2, wk2, bk2,
      hs, hall, partsA, cka);

  // P2: banded conv vs h_s with WKA  ||  grouped conv + relu (h1 -> h2)
  p2_kernel<<<384 + 1536, 256, 0, stream>>>(hs, partsA, rpart, w2, b2, hall);

  // P3: rreduce -> rbuf  ||  xs = w3@h2
  p3_kernel<<<168 + 96, 256, 0, stream>>>(rpart, cka, rbuf, hall, w3, b3, xs);

  // P4: softmax A-build (wave-per-column) -> At
  p4_kernel<<<384, 256, 0, stream>>>(rbuf, ba0, ba1, ba2, At);

  // P5: out0 = xs@A (transposed At staging)  ||  Aout = At^T
  p5_kernel<<<96 + 288, 256, 0, stream>>>(xs, At, out0, Aout);
}

// Round 13
// 80.990 us; speedup vs baseline: 13.5426x; 1.1155x over previous
//
#include <hip/hip_runtime.h>

#define T_LEN 192

// ===========================================================================
// ---- tiled GEMM body: Y[n,o,t] = sum_c W[o,c]*X[c,t] + B[o] ---------------
// TRANSX=false: X[c,t] = Xg[(n*cstr + c)*192 + t]
// TRANSX=true : X[c,u] = Xg[(n*192 + u)*192 + c]   (At layout, transposed)
// v2: register-prefetch double buffering — next K-tile's global loads issue
// right after this tile's LDS writes and retire during the 64-step FMA loop.
// ===========================================================================
template<bool TRANSX>
__device__ __forceinline__ void gemm_body(
    float* smem,
    const float* __restrict__ W, const float* __restrict__ B,
    const float* __restrict__ X, float* __restrict__ Y,
    int cin, int cstr, int ostr, int wnstr,
    int t0, int o0, int n, int tid)
{
  float (*Ws)[68] = (float(*)[68])smem;             // [c][o]
  float (*Xs)[68] = (float(*)[68])(smem + 64 * 68); // [c][t]
  const int to = tid >> 4, tt = tid & 15;
  float acc[4][4] = {};

  auto loadW = [&](int l, int c0) {
    int idx = l * 256 + tid; int rr = idx >> 4, c4 = idx & 15;
    return *reinterpret_cast<const float4*>(
        &W[(size_t)n * wnstr + (size_t)(o0 + rr) * cin + c0 + c4 * 4]);
  };
  auto loadX = [&](int l, int c0) {
    int idx = l * 256 + tid; int rr = idx >> 4, c4 = idx & 15;
    if (!TRANSX)
      return *reinterpret_cast<const float4*>(
          &X[((size_t)n * cstr + c0 + rr) * T_LEN + t0 + c4 * 4]);
    else
      return *reinterpret_cast<const float4*>(
          &X[((size_t)n * 192 + t0 + rr) * 192 + c0 + c4 * 4]);
  };

  float4 wreg[4], xreg[4];
#pragma unroll
  for (int l = 0; l < 4; ++l) { wreg[l] = loadW(l, 0); xreg[l] = loadX(l, 0); }

  for (int c0 = 0; c0 < cin; c0 += 64) {
    __syncthreads();     // previous compute done reading LDS
#pragma unroll
    for (int l = 0; l < 4; ++l) {
      int idx = l * 256 + tid;
      int rr = idx >> 4, c4 = idx & 15;
      float4 wv = wreg[l];
      Ws[c4 * 4 + 0][rr] = wv.x; Ws[c4 * 4 + 1][rr] = wv.y;
      Ws[c4 * 4 + 2][rr] = wv.z; Ws[c4 * 4 + 3][rr] = wv.w;
      if (!TRANSX) {
        *reinterpret_cast<float4*>(&Xs[rr][c4 * 4]) = xreg[l];
      } else {
        float4 xv = xreg[l];
        Xs[c4 * 4 + 0][rr] = xv.x; Xs[c4 * 4 + 1][rr] = xv.y;
        Xs[c4 * 4 + 2][rr] = xv.z; Xs[c4 * 4 + 3][rr] = xv.w;
      }
    }
    if (c0 + 64 < cin) {   // prefetch next tile into registers
#pragma unroll
      for (int l = 0; l < 4; ++l) {
        wreg[l] = loadW(l, c0 + 64);
        xreg[l] = loadX(l, c0 + 64);
      }
    }
    __syncthreads();
#pragma unroll
    for (int kk = 0; kk < 64; ++kk) {
      float4 a = *reinterpret_cast<const float4*>(&Ws[kk][to * 4]);
      float4 b = *reinterpret_cast<const float4*>(&Xs[kk][tt * 4]);
      acc[0][0] += a.x * b.x; acc[0][1] += a.x * b.y; acc[0][2] += a.x * b.z; acc[0][3] += a.x * b.w;
      acc[1][0] += a.y * b.x; acc[1][1] += a.y * b.y; acc[1][2] += a.y * b.z; acc[1][3] += a.y * b.w;
      acc[2][0] += a.z * b.x; acc[2][1] += a.z * b.y; acc[2][2] += a.z * b.z; acc[2][3] += a.z * b.w;
      acc[3][0] += a.w * b.x; acc[3][1] += a.w * b.y; acc[3][2] += a.w * b.z; acc[3][3] += a.w * b.w;
    }
  }
#pragma unroll
  for (int i = 0; i < 4; ++i) {
    float bi = B ? B[o0 + to * 4 + i] : 0.f;
    float4 v = make_float4(acc[i][0] + bi, acc[i][1] + bi, acc[i][2] + bi, acc[i][3] + bi);
    *reinterpret_cast<float4*>(
        &Y[((size_t)n * ostr + o0 + to * 4 + i) * T_LEN + t0 + tt * 4]) = v;
  }
}

// ===========================================================================
// foldA: parts[chunk][j*K+i][c'] = sum_{c in 16-chunk} wa[c,j]*wk[c,c',i]
// Barrier-free: thread = c' (256), block = (s, chunk of 16 c, j-group).
// ===========================================================================
template<int K, int JN>
__device__ __forceinline__ void foldA_body(
    const float* __restrict__ wa, const float* __restrict__ wk,
    float* __restrict__ parts, int j0, int chunk, int tid)
{
  float acc[JN][K];
#pragma unroll
  for (int jj = 0; jj < JN; ++jj)
#pragma unroll
    for (int i = 0; i < K; ++i) acc[jj][i] = 0.f;

  const int c0 = chunk * 16;
  for (int c = c0; c < c0 + 16; ++c) {
    const float* base = &wk[((size_t)c * 256 + tid) * K];
    float v[K];
#pragma unroll
    for (int i = 0; i < K; ++i) v[i] = base[i];
    float w[JN];
#pragma unroll
    for (int jj = 0; jj < JN; ++jj) w[jj] = wa[c * K + j0 + jj];
#pragma unroll
    for (int jj = 0; jj < JN; ++jj)
#pragma unroll
      for (int i = 0; i < K; ++i) acc[jj][i] += w[jj] * v[i];
  }
#pragma unroll
  for (int jj = 0; jj < JN; ++jj)
#pragma unroll
    for (int i = 0; i < K; ++i)
      parts[((size_t)chunk * K * K + (j0 + jj) * K + i) * 256 + tid] = acc[jj][i];
}

// ---- cka[s,j] = sum_c wa[c,j]*bk[c] ---------------------------------------
__device__ __forceinline__ void cka_body(
    const float* __restrict__ wa0, const float* __restrict__ bk0,
    const float* __restrict__ wa1, const float* __restrict__ bk1,
    const float* __restrict__ wa2, const float* __restrict__ bk2,
    float* __restrict__ cka, int tid)
{
  if (tid >= 21) return;
  int s, j, K; const float *wa, *bk;
  if (tid < 3)       { s = 0; j = tid;      K = 3;  wa = wa0; bk = bk0; }
  else if (tid < 10) { s = 1; j = tid - 3;  K = 7;  wa = wa1; bk = bk1; }
  else               { s = 2; j = tid - 10; K = 11; wa = wa2; bk = bk2; }
  float acc = 0.f;
  for (int c = 0; c < 128; ++c) acc += wa[c * K + j] * bk[c];
  cka[s * 11 + j] = acc;
}

// ===========================================================================
// foldB: stage chunk-summed WKA row in LDS, then coalesced wp GEMV.
// half==0 block also computes bpA[ji] via LDS dot.
// ===========================================================================
template<int K>
__device__ __forceinline__ void foldB_body(
    float* lds, const float* __restrict__ parts, const float* __restrict__ wp,
    const float* __restrict__ bp, float* __restrict__ wxas,
    float* __restrict__ bpA_s, int ji, int half, int tid)
{
  constexpr int KP = (K + 3) & ~3;
  constexpr int K2 = K * K;
  float s = 0.f;
#pragma unroll
  for (int ch = 0; ch < 8; ++ch)
    s += parts[((size_t)(ch * K2 + ji)) * 256 + tid];
  lds[tid] = s;
  __syncthreads();

  const int cin = half * 256 + tid;
  float acc = 0.f;
  for (int c = 0; c < 256; ++c)
    acc += lds[c] * wp[(size_t)c * 512 + cin];
  const int j = ji / K, i = ji - j * K;
  wxas[(size_t)cin * K * KP + i * KP + j] = acc;

  if (half == 0 && tid == 0) {
    float b = 0.f;
    for (int c = 0; c < 256; ++c) b += lds[c] * bp[c];
    bpA_s[j * 11 + i] = b;
  }
}

// ===========================================================================
// rcomp: rpart[n,cc,j,t] = sum_{16ch,i} WXA[c,i,j]*xpad[n,c,t+i-A]
// ===========================================================================
template<int A>
__device__ __forceinline__ void rcomp_body(
    float* smem, const float* __restrict__ x, const float* __restrict__ WXAs,
    float* __restrict__ rps, int cc, int n, int tid)
{
  constexpr int K  = 2 * A + 1;
  constexpr int KP = (K + 3) & ~3;
  constexpr int WH = 192 + 2 * A;
  constexpr int WS = 204;
  float* Xs = smem;               // 16 x 204
  float* Wl = smem + 16 * WS;     // 16 x K x KP
  const int c0 = cc * 16;

  for (int idx = tid; idx < 16 * WH; idx += 256) {
    int c = idx / WH, p = idx - c * WH;
    int tau = p - A;
    Xs[c * WS + p] = (tau >= 0 && tau < 192)
        ? x[((size_t)n * 512 + c0 + c) * 192 + tau] : 0.f;
  }
  {
    const float4* wg = reinterpret_cast<const float4*>(WXAs + (size_t)c0 * K * KP);
    float4* wl = reinterpret_cast<float4*>(Wl);
    for (int idx = tid; idx < 16 * K * KP / 4; idx += 256) wl[idx] = wg[idx];
  }
  __syncthreads();

  const int w = tid >> 6, lane = tid & 63;
  const int csub = lane >> 4, tpos = lane & 15;
  const int tb = w * 48 + tpos * 3;

  float acc[K][3];
#pragma unroll
  for (int j = 0; j < K; ++j) { acc[j][0] = 0.f; acc[j][1] = 0.f; acc[j][2] = 0.f; }

#pragma unroll
  for (int c = 0; c < 4; ++c) {
    const int ch = csub * 4 + c;
    float win[K + 2];
#pragma unroll
    for (int p = 0; p < K + 2; ++p) win[p] = Xs[ch * WS + tb + p];
    const float* wr = &Wl[ch * K * KP];
#pragma unroll
    for (int i = 0; i < K; ++i) {
#pragma unroll
      for (int j = 0; j < K; ++j) {
        float wv = wr[i * KP + j];
        acc[j][0] += wv * win[i + 0];
        acc[j][1] += wv * win[i + 1];
        acc[j][2] += wv * win[i + 2];
      }
    }
  }
#pragma unroll
  for (int j = 0; j < K; ++j) {
#pragma unroll
    for (int q = 0; q < 3; ++q) {
      float v = acc[j][q];
      v += __shfl_xor(v, 16);
      v += __shfl_xor(v, 32);
      acc[j][q] = v;
    }
  }
  if (csub == 0) {
#pragma unroll
    for (int j = 0; j < K; ++j) {
      float* dst = &rps[(((size_t)n * 32 + cc) * K + j) * 192 + tb];
      dst[0] = acc[j][0]; dst[1] = acc[j][1]; dst[2] = acc[j][2];
    }
  }
}

// ---- rreduce: rbuf[s,n,j,t] = sum_cc rpart + cka + boundary bp term -------
__device__ __forceinline__ void rreduce_body(
    const float* __restrict__ rpart, const float* __restrict__ cka,
    const float* __restrict__ bpA, float* __restrict__ rbuf,
    int n, int sj, int t)
{
  if (t >= 192) return;
  const int s = sj < 3 ? 0 : sj < 10 ? 1 : 2;
  const int j = sj < 3 ? sj : sj < 10 ? sj - 3 : sj - 10;
  const int A = (s == 0) ? 1 : (s == 1) ? 3 : 5;
  const int K = 2 * A + 1;
  const int roff = (s == 0) ? 0 : (s == 1) ? 147456 : 491520;
  const float* rp = rpart + roff;
  float acc = cka[s * 11 + j];
#pragma unroll 8
  for (int cc = 0; cc < 32; ++cc)
    acc += rp[(((size_t)n * 32 + cc) * K + j) * 192 + t];
  for (int i = 0; i < K; ++i) {
    int tau = t + i - A;
    if (tau >= 0 && tau < 192) acc += bpA[s * 121 + j * 11 + i];
  }
  rbuf[((size_t)(s * 8 + n) * 11 + j) * 192 + t] = acc;
}

// ===========================================================================
// abuild: 1 wave = 1 softmax column u; 64 lanes x 3 t; shfl-only
// ===========================================================================
template<int A>
__device__ __forceinline__ float gather_val(const float* __restrict__ rs,
                                            int t, int u)
{
  constexpr int K = 2 * A + 1;
  float val = 0.f;
#pragma unroll
  for (int j = 0; j < K; ++j) {
    int tp = t + j - A;
    int d = tp - u;
    if (tp >= 0 && tp < 192 && d <= A && d >= -A) val += rs[j * 192 + tp];
  }
  return val;
}

__device__ __forceinline__ void abuild_body(
    const float* __restrict__ rbuf,
    const float* __restrict__ ba0, const float* __restrict__ ba1,
    const float* __restrict__ ba2, float* __restrict__ At,
    int ublk, int n, int tid)
{
  const int w = tid >> 6, lane = tid & 63;
  const int u = ublk * 4 + w;
  const int t0 = lane * 3;
  const float* r0 = rbuf + (size_t)(0 * 8 + n) * 11 * 192;
  const float* r1 = rbuf + (size_t)(1 * 8 + n) * 11 * 192;
  const float* r2 = rbuf + (size_t)(2 * 8 + n) * 11 * 192;
  float v0[3], v1[3], v2[3];
  const float b0 = ba0[0], b1 = ba1[0], b2 = ba2[0];
#pragma unroll
  for (int q = 0; q < 3; ++q) {
    v0[q] = b0 + gather_val<1>(r0, t0 + q, u);
    v1[q] = b1 + gather_val<3>(r1, t0 + q, u);
    v2[q] = b2 + gather_val<5>(r2, t0 + q, u);
  }
  float m0 = fmaxf(fmaxf(v0[0], v0[1]), v0[2]);
  float m1 = fmaxf(fmaxf(v1[0], v1[1]), v1[2]);
  float m2 = fmaxf(fmaxf(v2[0], v2[1]), v2[2]);
#pragma unroll
  for (int off = 32; off > 0; off >>= 1) {
    m0 = fmaxf(m0, __shfl_xor(m0, off));
    m1 = fmaxf(m1, __shfl_xor(m1, off));
    m2 = fmaxf(m2, __shfl_xor(m2, off));
  }
  float e0[3], e1[3], e2[3];
#pragma unroll
  for (int q = 0; q < 3; ++q) {
    e0[q] = __expf(v0[q] - m0);
    e1[q] = __expf(v1[q] - m1);
    e2[q] = __expf(v2[q] - m2);
  }
  float s0 = e0[0] + e0[1] + e0[2];
  float s1 = e1[0] + e1[1] + e1[2];
  float s2 = e2[0] + e2[1] + e2[2];
#pragma unroll
  for (int off = 32; off > 0; off >>= 1) {
    s0 += __shfl_xor(s0, off);
    s1 += __shfl_xor(s1, off);
    s2 += __shfl_xor(s2, off);
  }
  const float i0 = 1.f / s0, i1 = 1.f / s1, i2 = 1.f / s2;
  float* dst = &At[((size_t)n * 192 + u) * 192 + t0];
#pragma unroll
  for (int q = 0; q < 3; ++q)
    dst[q] = e0[q] * i0 + e1[q] * i1 + e2[q] * i2;
}

// ---- grouped conv (groups=32, K=3) + ReLU ---------------------------------
__device__ __forceinline__ void gconv_body(
    const float* __restrict__ hin, const float* __restrict__ w2,
    const float* __restrict__ b2, float* __restrict__ hout,
    int bx, int by, int n, int tid)
{
  const int t  = (tid & 63) + bx * 64;
  const int oc = (tid >> 6) + by * 4;
  const int g  = oc >> 3;
  float acc = b2[oc];
  for (int i = 0; i < 8; ++i) {
    const float* hrow = &hin[((size_t)n * 512 + g * 8 + i) * 192];
#pragma unroll
    for (int j = 0; j < 3; ++j) {
      int tt = t + j - 1;
      float hv = (tt >= 0 && tt < 192) ? hrow[tt] : 0.f;
      acc += w2[((size_t)oc * 8 + i) * 3 + j] * hv;
    }
  }
  hout[((size_t)n * 512 + 256 + oc) * 192 + t] = fmaxf(acc, 0.f);
}

// ---- At[n][u][t] -> Aout[n][t][u] ------------------------------------------
__device__ __forceinline__ void transpose_body(
    float* smem, const float* __restrict__ At, float* __restrict__ Aout,
    int bx, int by, int n, int tid)
{
  float (*tile)[33] = (float(*)[33])smem;
  const int xx = tid & 31, y = tid >> 5;
  for (int yy = y; yy < 32; yy += 8)
    tile[yy][xx] = At[((size_t)n * 192 + by * 32 + yy) * 192 + bx * 32 + xx];
  __syncthreads();
  for (int yy = y; yy < 32; yy += 8)
    Aout[((size_t)n * 192 + bx * 32 + yy) * 192 + by * 32 + xx] = tile[xx][yy];
}

// ===========================================================================
// K0a: foldA (48) + cka (1)
// ===========================================================================
__global__ __launch_bounds__(256) void fold_a(
    const float* __restrict__ wa0, const float* __restrict__ wk0,
    const float* __restrict__ bk0,
    const float* __restrict__ wa1, const float* __restrict__ wk1,
    const float* __restrict__ bk1,
    const float* __restrict__ wa2, const float* __restrict__ wk2,
    const float* __restrict__ bk2,
    float* __restrict__ partsA, float* __restrict__ cka)
{
  const int bid = blockIdx.x, tid = threadIdx.x;
  if (bid < 48) {
    const int s = bid >> 4, sub = bid & 15;
    const int chunk = sub >> 1, jg = sub & 1;
    if (s == 0) {
      if (jg == 0) foldA_body<3, 2>(wa0, wk0, partsA,          0, chunk, tid);
      else         foldA_body<3, 1>(wa0, wk0, partsA,          2, chunk, tid);
    } else if (s == 1) {
      if (jg == 0) foldA_body<7, 4>(wa1, wk1, partsA + 18432,  0, chunk, tid);
      else         foldA_body<7, 3>(wa1, wk1, partsA + 18432,  4, chunk, tid);
    } else {
      if (jg == 0) foldA_body<11, 6>(wa2, wk2, partsA + 118784, 0, chunk, tid);
      else         foldA_body<11, 5>(wa2, wk2, partsA + 118784, 6, chunk, tid);
    }
  } else {
    cka_body(wa0, bk0, wa1, bk1, wa2, bk2, cka, tid);
  }
}

// ===========================================================================
// K0b: foldB (358) — LDS-staged WKA row; bpA inline in half==0 blocks
// ===========================================================================
__global__ __launch_bounds__(256) void fold_b(
    const float* __restrict__ partsA,
    const float* __restrict__ wp0, const float* __restrict__ bp0,
    const float* __restrict__ wp1, const float* __restrict__ bp1,
    const float* __restrict__ wp2, const float* __restrict__ bp2,
    float* __restrict__ WXA, float* __restrict__ bpA)
{
  __shared__ float lds[256];
  const int bid = blockIdx.x, tid = threadIdx.x;
  if (bid < 18)
    foldB_body<3>(lds, partsA, wp0, bp0, WXA, bpA,
                  bid >> 1, bid & 1, tid);
  else if (bid < 116)
    foldB_body<7>(lds, partsA + 18432, wp1, bp1, WXA + 6144, bpA + 121,
                  (bid - 18) >> 1, (bid - 18) & 1, tid);
  else
    foldB_body<11>(lds, partsA + 118784, wp2, bp2, WXA + 34816, bpA + 242,
                   (bid - 116) >> 1, (bid - 116) & 1, tid);
}

// ===========================================================================
// K2: gemm h1 (96)  ||  rcomp (768)
// ===========================================================================
__global__ __launch_bounds__(256) void k2_kernel(
    const float* __restrict__ x, const float* __restrict__ w1,
    const float* __restrict__ b1, const float* __restrict__ WXA,
    float* __restrict__ hall, float* __restrict__ rpart)
{
  __shared__ __align__(16) float smem[8704];
  const int bid = blockIdx.x, tid = threadIdx.x;
  if (bid < 96) {
    const int tx = bid % 3, oy = (bid / 3) % 4, n = bid / 12;
    gemm_body<false>(smem, w1, b1, x, hall, 512, 512, 512, 0,
                     tx * 64, oy * 64, n, tid);
  } else {
    const int rid = bid - 96;
    const int cc = rid % 32, n = (rid / 32) % 8, s = rid / 256;
    if (s == 0)      rcomp_body<1>(smem, x, WXA,         rpart,          cc, n, tid);
    else if (s == 1) rcomp_body<3>(smem, x, WXA + 6144,  rpart + 147456, cc, n, tid);
    else             rcomp_body<5>(smem, x, WXA + 34816, rpart + 491520, cc, n, tid);
  }
}

// ===========================================================================
// K3: rreduce (168)  ||  gconv (1536)
// ===========================================================================
__global__ __launch_bounds__(256) void k3_kernel(
    const float* __restrict__ rpart, const float* __restrict__ cka,
    const float* __restrict__ bpA, float* __restrict__ rbuf,
    const float* __restrict__ w2, const float* __restrict__ b2,
    float* __restrict__ hall)
{
  const int bid = blockIdx.x, tid = threadIdx.x;
  if (bid < 168) {
    rreduce_body(rpart, cka, bpA, rbuf, bid % 8, bid / 8, tid);
  } else {
    const int gid = bid - 168;
    gconv_body(hall, w2, b2, hall, gid % 3, (gid / 3) % 64, gid / 192, tid);
  }
}

// ===========================================================================
// K4: abuild (384)  ||  gemm w3 (96)
// ===========================================================================
__global__ __launch_bounds__(256) void k4_kernel(
    const float* __restrict__ rbuf,
    const float* __restrict__ ba0, const float* __restrict__ ba1,
    const float* __restrict__ ba2, float* __restrict__ At,
    const float* __restrict__ hall, const float* __restrict__ w3,
    const float* __restrict__ b3, float* __restrict__ xs)
{
  __shared__ __align__(16) float smem[8704];
  const int bid = blockIdx.x, tid = threadIdx.x;
  if (bid < 384) {
    abuild_body(rbuf, ba0, ba1, ba2, At, bid % 48, bid / 48, tid);
  } else {
    const int gid = bid - 384;
    const int tx = gid % 3, oy = (gid / 3) % 4, n = gid / 12;
    gemm_body<false>(smem, w3, b3, hall + 256 * 192, xs, 256, 512, 256, 0,
                     tx * 64, oy * 64, n, tid);
  }
}

// ===========================================================================
// K5: out0 = xs@A (96, At read transposed)  ||  transpose (288)
// ===========================================================================
__global__ __launch_bounds__(256) void k5_kernel(
    const float* __restrict__ xs, const float* __restrict__ At,
    float* __restrict__ out0, float* __restrict__ Aout)
{
  __shared__ __align__(16) float smem[8704];
  const int bid = blockIdx.x, tid = threadIdx.x;
  if (bid < 96) {
    const int tx = bid % 3, oy = (bid / 3) % 4, n = bid / 12;
    gemm_body<true>(smem, xs, nullptr, At, out0, 192, 0, 256, 256 * 192,
                    tx * 64, oy * 64, n, tid);
  } else {
    const int gid = bid - 96;
    transpose_body(smem, At, Aout, gid % 6, (gid / 6) % 6, gid / 36, tid);
  }
}

// ===========================================================================
extern "C" void kernel_launch(void* const* d_in, const int* in_sizes, int n_in,
                              void* d_out, int out_size, void* d_ws, size_t ws_size,
                              hipStream_t stream)
{
  const float* x   = (const float*)d_in[0];
  const float* wp0 = (const float*)d_in[1];
  const float* bp0 = (const float*)d_in[2];
  const float* wk0 = (const float*)d_in[3];
  const float* bk0 = (const float*)d_in[4];
  const float* wa0 = (const float*)d_in[5];
  const float* ba0 = (const float*)d_in[6];
  const float* wp1 = (const float*)d_in[7];
  const float* bp1 = (const float*)d_in[8];
  const float* wk1 = (const float*)d_in[9];
  const float* bk1 = (const float*)d_in[10];
  const float* wa1 = (const float*)d_in[11];
  const float* ba1 = (const float*)d_in[12];
  const float* wp2 = (const float*)d_in[13];
  const float* bp2 = (const float*)d_in[14];
  const float* wk2 = (const float*)d_in[15];
  const float* bk2 = (const float*)d_in[16];
  const float* wa2 = (const float*)d_in[17];
  const float* ba2 = (const float*)d_in[18];
  const float* w1  = (const float*)d_in[19];
  const float* b1  = (const float*)d_in[20];
  const float* w2  = (const float*)d_in[21];
  const float* b2  = (const float*)d_in[22];
  const float* w3  = (const float*)d_in[23];
  const float* b3  = (const float*)d_in[24];

  float* ws     = (float*)d_ws;
  float* hall   = ws;                         // [8][512][192]        =   786,432
  float* At     = hall   + 786432;            // [8][192][192]        =   294,912
  float* xs     = At     + 294912;            // [8][256][192]        =   393,216
  float* rpart  = xs     + 393216;            // [8][32][3+7+11][192] = 1,032,192
  float* rbuf   = rpart  + 1032192;           // [3][8][11][192]      =    50,688
  float* WXA    = rbuf   + 50688;             // [512]*(12+56+132)    =   102,400
  float* bpA    = WXA    + 102400;            // [3][121]             =       384
  float* cka    = bpA    + 384;               // [3][11] (pad 64)     =        64
  float* partsA = cka    + 64;                // 8*(9+49+121)*256     =   366,592
  float* out0   = (float*)d_out;              // [8][256][192]
  float* Aout   = out0 + 8 * 256 * 192;       // [8][192][192]

  // K0a: foldA partial WKA (barrier-free, coalesced wk)  +  cka
  fold_a<<<49, 256, 0, stream>>>(
      wa0, wk0, bk0, wa1, wk1, bk1, wa2, wk2, bk2, partsA, cka);

  // K0b: foldB -> WXA (LDS-staged row) + bpA
  fold_b<<<358, 256, 0, stream>>>(
      partsA, wp0, bp0, wp1, bp1, wp2, bp2, WXA, bpA);

  // K2: h1 = w1@x  ||  banded rcomp on x
  k2_kernel<<<96 + 768, 256, 0, stream>>>(x, w1, b1, WXA, hall, rpart);

  // K3: rreduce  ||  grouped conv + relu (h1 -> h2)
  k3_kernel<<<168 + 1536, 256, 0, stream>>>(rpart, cka, bpA, rbuf, w2, b2, hall);

  // K4: softmax A-build (wave-per-column)  ||  xs = w3@h2
  k4_kernel<<<384 + 96, 256, 0, stream>>>(rbuf, ba0, ba1, ba2, At,
                                          hall, w3, b3, xs);

  // K5: out0 = xs@A (transposed At staging)  ||  Aout = At^T
  k5_kernel<<<96 + 288, 256, 0, stream>>>(xs, At, out0, Aout);
}

// Round 14
// 72.006 us; speedup vs baseline: 15.2323x; 1.1248x over previous
//
#include <hip/hip_runtime.h>

#define T_LEN 192

// ===========================================================================
// ---- tiled GEMM body v3: Y[n,o,t] = sum_c W[o,c]*X[c,t] + B[o] ------------
// TRANSX=false: X[c,t] = Xg[(n*cstr + c)*192 + t]
// TRANSX=true : X[c,u] = Xg[(n*192 + u)*192 + c]   (At layout, transposed)
// Tile 32(o) x 64(t) x 64(c); 256 thr; micro 2o x 4t; register prefetch.
// LDS tiles XOR-swizzled (col' = col ^ 4*((row>>2)&7)) -> conflict-free
// scatter stores (old layout was ~8-way conflicted: 2.75M cycles in R12 p1).
// ===========================================================================
template<bool TRANSX>
__device__ __forceinline__ void gemm_body(
    float* smem,
    const float* __restrict__ W, const float* __restrict__ B,
    const float* __restrict__ X, float* __restrict__ Y,
    int cin, int cstr, int ostr, int wnstr,
    int t0, int o0, int n, int tid)
{
  float* Ws = smem;                                  // [64][32] swizzled
  float (*Xs)[68] = (float(*)[68])(smem + 2048);     // [64][68] swizzled
  const int to = tid >> 4, tt = tid & 15;
  float acc[2][4] = {};

  auto loadW = [&](int l, int c0) {
    int idx = l * 256 + tid; int rr = idx >> 4, c4 = idx & 15;
    return *reinterpret_cast<const float4*>(
        &W[(size_t)n * wnstr + (size_t)(o0 + rr) * cin + c0 + c4 * 4]);
  };
  auto loadX = [&](int l, int c0) {
    int idx = l * 256 + tid; int rr = idx >> 4, c4 = idx & 15;
    if (!TRANSX)
      return *reinterpret_cast<const float4*>(
          &X[((size_t)n * cstr + c0 + rr) * T_LEN + t0 + c4 * 4]);
    else
      return *reinterpret_cast<const float4*>(
          &X[((size_t)n * 192 + t0 + rr) * 192 + c0 + c4 * 4]);
  };

  float4 wreg[2], xreg[4];
#pragma unroll
  for (int l = 0; l < 2; ++l) wreg[l] = loadW(l, 0);
#pragma unroll
  for (int l = 0; l < 4; ++l) xreg[l] = loadX(l, 0);

  for (int c0 = 0; c0 < cin; c0 += 64) {
    __syncthreads();     // previous compute done reading LDS
    // ---- stage W: [c][o] scatter, swizzled ----
#pragma unroll
    for (int l = 0; l < 2; ++l) {
      int idx = l * 256 + tid;
      int rr = idx >> 4, c4 = idx & 15;          // rr = o-local, c4 = c-group
      float4 wv = wreg[l];
      const int sw = 4 * (c4 & 7);
      Ws[(c4 * 4 + 0) * 32 + (rr ^ sw)] = wv.x;
      Ws[(c4 * 4 + 1) * 32 + (rr ^ sw)] = wv.y;
      Ws[(c4 * 4 + 2) * 32 + (rr ^ sw)] = wv.z;
      Ws[(c4 * 4 + 3) * 32 + (rr ^ sw)] = wv.w;
    }
    // ---- stage X: [c][t], swizzled ----
#pragma unroll
    for (int l = 0; l < 4; ++l) {
      int idx = l * 256 + tid;
      int rr = idx >> 4, c4 = idx & 15;
      if (!TRANSX) {                              // rr = c, c4 = t-group
        *reinterpret_cast<float4*>(
            &Xs[rr][(c4 * 4) ^ (4 * ((rr >> 2) & 7))]) = xreg[l];
      } else {                                    // rr = t, c4 = c-group
        float4 xv = xreg[l];
        const int sw = 4 * (c4 & 7);
        Xs[c4 * 4 + 0][rr ^ sw] = xv.x;
        Xs[c4 * 4 + 1][rr ^ sw] = xv.y;
        Xs[c4 * 4 + 2][rr ^ sw] = xv.z;
        Xs[c4 * 4 + 3][rr ^ sw] = xv.w;
      }
    }
    if (c0 + 64 < cin) {   // prefetch next tile into registers
#pragma unroll
      for (int l = 0; l < 2; ++l) wreg[l] = loadW(l, c0 + 64);
#pragma unroll
      for (int l = 0; l < 4; ++l) xreg[l] = loadX(l, c0 + 64);
    }
    __syncthreads();
#pragma unroll
    for (int kk = 0; kk < 64; ++kk) {
      const int sw = 4 * ((kk >> 2) & 7);
      float2 a = *reinterpret_cast<const float2*>(
          &Ws[kk * 32 + ((to * 2) ^ sw)]);
      float4 b = *reinterpret_cast<const float4*>(
          &Xs[kk][(tt * 4) ^ sw]);
      acc[0][0] += a.x * b.x; acc[0][1] += a.x * b.y;
      acc[0][2] += a.x * b.z; acc[0][3] += a.x * b.w;
      acc[1][0] += a.y * b.x; acc[1][1] += a.y * b.y;
      acc[1][2] += a.y * b.z; acc[1][3] += a.y * b.w;
    }
  }
#pragma unroll
  for (int i = 0; i < 2; ++i) {
    float bi = B ? B[o0 + to * 2 + i] : 0.f;
    float4 v = make_float4(acc[i][0] + bi, acc[i][1] + bi,
                           acc[i][2] + bi, acc[i][3] + bi);
    *reinterpret_cast<float4*>(
        &Y[((size_t)n * ostr + o0 + to * 2 + i) * T_LEN + t0 + tt * 4]) = v;
  }
}

// ===========================================================================
// foldA: parts[chunk][j*K+i][c'] = sum_{c in 16-chunk} wa[c,j]*wk[c,c',i]
// Barrier-free: thread = c' (256), block = (s, chunk of 16 c, j-group).
// ===========================================================================
template<int K, int JN>
__device__ __forceinline__ void foldA_body(
    const float* __restrict__ wa, const float* __restrict__ wk,
    float* __restrict__ parts, int j0, int chunk, int tid)
{
  float acc[JN][K];
#pragma unroll
  for (int jj = 0; jj < JN; ++jj)
#pragma unroll
    for (int i = 0; i < K; ++i) acc[jj][i] = 0.f;

  const int c0 = chunk * 16;
  for (int c = c0; c < c0 + 16; ++c) {
    const float* base = &wk[((size_t)c * 256 + tid) * K];
    float v[K];
#pragma unroll
    for (int i = 0; i < K; ++i) v[i] = base[i];
    float w[JN];
#pragma unroll
    for (int jj = 0; jj < JN; ++jj) w[jj] = wa[c * K + j0 + jj];
#pragma unroll
    for (int jj = 0; jj < JN; ++jj)
#pragma unroll
      for (int i = 0; i < K; ++i) acc[jj][i] += w[jj] * v[i];
  }
#pragma unroll
  for (int jj = 0; jj < JN; ++jj)
#pragma unroll
    for (int i = 0; i < K; ++i)
      parts[((size_t)chunk * K * K + (j0 + jj) * K + i) * 256 + tid] = acc[jj][i];
}

// ---- cka[s,j] = sum_c wa[c,j]*bk[c] ---------------------------------------
__device__ __forceinline__ void cka_body(
    const float* __restrict__ wa0, const float* __restrict__ bk0,
    const float* __restrict__ wa1, const float* __restrict__ bk1,
    const float* __restrict__ wa2, const float* __restrict__ bk2,
    float* __restrict__ cka, int tid)
{
  if (tid >= 21) return;
  int s, j, K; const float *wa, *bk;
  if (tid < 3)       { s = 0; j = tid;      K = 3;  wa = wa0; bk = bk0; }
  else if (tid < 10) { s = 1; j = tid - 3;  K = 7;  wa = wa1; bk = bk1; }
  else               { s = 2; j = tid - 10; K = 11; wa = wa2; bk = bk2; }
  float acc = 0.f;
  for (int c = 0; c < 128; ++c) acc += wa[c * K + j] * bk[c];
  cka[s * 11 + j] = acc;
}

// ===========================================================================
// foldB: stage chunk-summed WKA row in LDS, then coalesced wp GEMV.
// half==0 block also computes bpA[ji] via LDS dot.
// ===========================================================================
template<int K>
__device__ __forceinline__ void foldB_body(
    float* lds, const float* __restrict__ parts, const float* __restrict__ wp,
    const float* __restrict__ bp, float* __restrict__ wxas,
    float* __restrict__ bpA_s, int ji, int half, int tid)
{
  constexpr int KP = (K + 3) & ~3;
  constexpr int K2 = K * K;
  float s = 0.f;
#pragma unroll
  for (int ch = 0; ch < 8; ++ch)
    s += parts[((size_t)(ch * K2 + ji)) * 256 + tid];
  lds[tid] = s;
  __syncthreads();

  const int cin = half * 256 + tid;
  float acc = 0.f;
  for (int c = 0; c < 256; ++c)
    acc += lds[c] * wp[(size_t)c * 512 + cin];
  const int j = ji / K, i = ji - j * K;
  wxas[(size_t)cin * K * KP + i * KP + j] = acc;

  if (half == 0 && tid == 0) {
    float b = 0.f;
    for (int c = 0; c < 256; ++c) b += lds[c] * bp[c];
    bpA_s[j * 11 + i] = b;
  }
}

// ===========================================================================
// rcomp: rpart[n,cc,j,t] = sum_{16ch,i} WXA[c,i,j]*xpad[n,c,t+i-A]
// ===========================================================================
template<int A>
__device__ __forceinline__ void rcomp_body(
    float* smem, const float* __restrict__ x, const float* __restrict__ WXAs,
    float* __restrict__ rps, int cc, int n, int tid)
{
  constexpr int K  = 2 * A + 1;
  constexpr int KP = (K + 3) & ~3;
  constexpr int WH = 192 + 2 * A;
  constexpr int WS = 204;
  float* Xs = smem;               // 16 x 204
  float* Wl = smem + 16 * WS;     // 16 x K x KP
  const int c0 = cc * 16;

  for (int idx = tid; idx < 16 * WH; idx += 256) {
    int c = idx / WH, p = idx - c * WH;
    int tau = p - A;
    Xs[c * WS + p] = (tau >= 0 && tau < 192)
        ? x[((size_t)n * 512 + c0 + c) * 192 + tau] : 0.f;
  }
  {
    const float4* wg = reinterpret_cast<const float4*>(WXAs + (size_t)c0 * K * KP);
    float4* wl = reinterpret_cast<float4*>(Wl);
    for (int idx = tid; idx < 16 * K * KP / 4; idx += 256) wl[idx] = wg[idx];
  }
  __syncthreads();

  const int w = tid >> 6, lane = tid & 63;
  const int csub = lane >> 4, tpos = lane & 15;
  const int tb = w * 48 + tpos * 3;

  float acc[K][3];
#pragma unroll
  for (int j = 0; j < K; ++j) { acc[j][0] = 0.f; acc[j][1] = 0.f; acc[j][2] = 0.f; }

#pragma unroll
  for (int c = 0; c < 4; ++c) {
    const int ch = csub * 4 + c;
    float win[K + 2];
#pragma unroll
    for (int p = 0; p < K + 2; ++p) win[p] = Xs[ch * WS + tb + p];
    const float* wr = &Wl[ch * K * KP];
#pragma unroll
    for (int i = 0; i < K; ++i) {
#pragma unroll
      for (int j = 0; j < K; ++j) {
        float wv = wr[i * KP + j];
        acc[j][0] += wv * win[i + 0];
        acc[j][1] += wv * win[i + 1];
        acc[j][2] += wv * win[i + 2];
      }
    }
  }
#pragma unroll
  for (int j = 0; j < K; ++j) {
#pragma unroll
    for (int q = 0; q < 3; ++q) {
      float v = acc[j][q];
      v += __shfl_xor(v, 16);
      v += __shfl_xor(v, 32);
      acc[j][q] = v;
    }
  }
  if (csub == 0) {
#pragma unroll
    for (int j = 0; j < K; ++j) {
      float* dst = &rps[(((size_t)n * 32 + cc) * K + j) * 192 + tb];
      dst[0] = acc[j][0]; dst[1] = acc[j][1]; dst[2] = acc[j][2];
    }
  }
}

// ---- rreduce: rbuf[s,n,j,t] = sum_cc rpart + cka + boundary bp term -------
__device__ __forceinline__ void rreduce_body(
    const float* __restrict__ rpart, const float* __restrict__ cka,
    const float* __restrict__ bpA, float* __restrict__ rbuf,
    int n, int sj, int t)
{
  if (t >= 192) return;
  const int s = sj < 3 ? 0 : sj < 10 ? 1 : 2;
  const int j = sj < 3 ? sj : sj < 10 ? sj - 3 : sj - 10;
  const int A = (s == 0) ? 1 : (s == 1) ? 3 : 5;
  const int K = 2 * A + 1;
  const int roff = (s == 0) ? 0 : (s == 1) ? 147456 : 491520;
  const float* rp = rpart + roff;
  float acc = cka[s * 11 + j];
#pragma unroll 8
  for (int cc = 0; cc < 32; ++cc)
    acc += rp[(((size_t)n * 32 + cc) * K + j) * 192 + t];
  for (int i = 0; i < K; ++i) {
    int tau = t + i - A;
    if (tau >= 0 && tau < 192) acc += bpA[s * 121 + j * 11 + i];
  }
  rbuf[((size_t)(s * 8 + n) * 11 + j) * 192 + t] = acc;
}

// ===========================================================================
// abuild: 1 wave = 1 softmax column u; 64 lanes x 3 t; shfl-only
// ===========================================================================
template<int A>
__device__ __forceinline__ float gather_val(const float* __restrict__ rs,
                                            int t, int u)
{
  constexpr int K = 2 * A + 1;
  float val = 0.f;
#pragma unroll
  for (int j = 0; j < K; ++j) {
    int tp = t + j - A;
    int d = tp - u;
    if (tp >= 0 && tp < 192 && d <= A && d >= -A) val += rs[j * 192 + tp];
  }
  return val;
}

__device__ __forceinline__ void abuild_body(
    const float* __restrict__ rbuf,
    const float* __restrict__ ba0, const float* __restrict__ ba1,
    const float* __restrict__ ba2, float* __restrict__ At,
    int ublk, int n, int tid)
{
  const int w = tid >> 6, lane = tid & 63;
  const int u = ublk * 4 + w;
  const int t0 = lane * 3;
  const float* r0 = rbuf + (size_t)(0 * 8 + n) * 11 * 192;
  const float* r1 = rbuf + (size_t)(1 * 8 + n) * 11 * 192;
  const float* r2 = rbuf + (size_t)(2 * 8 + n) * 11 * 192;
  float v0[3], v1[3], v2[3];
  const float b0 = ba0[0], b1 = ba1[0], b2 = ba2[0];
#pragma unroll
  for (int q = 0; q < 3; ++q) {
    v0[q] = b0 + gather_val<1>(r0, t0 + q, u);
    v1[q] = b1 + gather_val<3>(r1, t0 + q, u);
    v2[q] = b2 + gather_val<5>(r2, t0 + q, u);
  }
  float m0 = fmaxf(fmaxf(v0[0], v0[1]), v0[2]);
  float m1 = fmaxf(fmaxf(v1[0], v1[1]), v1[2]);
  float m2 = fmaxf(fmaxf(v2[0], v2[1]), v2[2]);
#pragma unroll
  for (int off = 32; off > 0; off >>= 1) {
    m0 = fmaxf(m0, __shfl_xor(m0, off));
    m1 = fmaxf(m1, __shfl_xor(m1, off));
    m2 = fmaxf(m2, __shfl_xor(m2, off));
  }
  float e0[3], e1[3], e2[3];
#pragma unroll
  for (int q = 0; q < 3; ++q) {
    e0[q] = __expf(v0[q] - m0);
    e1[q] = __expf(v1[q] - m1);
    e2[q] = __expf(v2[q] - m2);
  }
  float s0 = e0[0] + e0[1] + e0[2];
  float s1 = e1[0] + e1[1] + e1[2];
  float s2 = e2[0] + e2[1] + e2[2];
#pragma unroll
  for (int off = 32; off > 0; off >>= 1) {
    s0 += __shfl_xor(s0, off);
    s1 += __shfl_xor(s1, off);
    s2 += __shfl_xor(s2, off);
  }
  const float i0 = 1.f / s0, i1 = 1.f / s1, i2 = 1.f / s2;
  float* dst = &At[((size_t)n * 192 + u) * 192 + t0];
#pragma unroll
  for (int q = 0; q < 3; ++q)
    dst[q] = e0[q] * i0 + e1[q] * i1 + e2[q] * i2;
}

// ---- grouped conv (groups=32, K=3) + ReLU ---------------------------------
__device__ __forceinline__ void gconv_body(
    const float* __restrict__ hin, const float* __restrict__ w2,
    const float* __restrict__ b2, float* __restrict__ hout,
    int bx, int by, int n, int tid)
{
  const int t  = (tid & 63) + bx * 64;
  const int oc = (tid >> 6) + by * 4;
  const int g  = oc >> 3;
  float acc = b2[oc];
  for (int i = 0; i < 8; ++i) {
    const float* hrow = &hin[((size_t)n * 512 + g * 8 + i) * 192];
#pragma unroll
    for (int j = 0; j < 3; ++j) {
      int tt = t + j - 1;
      float hv = (tt >= 0 && tt < 192) ? hrow[tt] : 0.f;
      acc += w2[((size_t)oc * 8 + i) * 3 + j] * hv;
    }
  }
  hout[((size_t)n * 512 + 256 + oc) * 192 + t] = fmaxf(acc, 0.f);
}

// ---- At[n][u][t] -> Aout[n][t][u] ------------------------------------------
__device__ __forceinline__ void transpose_body(
    float* smem, const float* __restrict__ At, float* __restrict__ Aout,
    int bx, int by, int n, int tid)
{
  float (*tile)[33] = (float(*)[33])smem;
  const int xx = tid & 31, y = tid >> 5;
  for (int yy = y; yy < 32; yy += 8)
    tile[yy][xx] = At[((size_t)n * 192 + by * 32 + yy) * 192 + bx * 32 + xx];
  __syncthreads();
  for (int yy = y; yy < 32; yy += 8)
    Aout[((size_t)n * 192 + bx * 32 + yy) * 192 + by * 32 + xx] = tile[xx][yy];
}

// ===========================================================================
// K0a: foldA (48) + cka (1)
// ===========================================================================
__global__ __launch_bounds__(256) void fold_a(
    const float* __restrict__ wa0, const float* __restrict__ wk0,
    const float* __restrict__ bk0,
    const float* __restrict__ wa1, const float* __restrict__ wk1,
    const float* __restrict__ bk1,
    const float* __restrict__ wa2, const float* __restrict__ wk2,
    const float* __restrict__ bk2,
    float* __restrict__ partsA, float* __restrict__ cka)
{
  const int bid = blockIdx.x, tid = threadIdx.x;
  if (bid < 48) {
    const int s = bid >> 4, sub = bid & 15;
    const int chunk = sub >> 1, jg = sub & 1;
    if (s == 0) {
      if (jg == 0) foldA_body<3, 2>(wa0, wk0, partsA,          0, chunk, tid);
      else         foldA_body<3, 1>(wa0, wk0, partsA,          2, chunk, tid);
    } else if (s == 1) {
      if (jg == 0) foldA_body<7, 4>(wa1, wk1, partsA + 18432,  0, chunk, tid);
      else         foldA_body<7, 3>(wa1, wk1, partsA + 18432,  4, chunk, tid);
    } else {
      if (jg == 0) foldA_body<11, 6>(wa2, wk2, partsA + 118784, 0, chunk, tid);
      else         foldA_body<11, 5>(wa2, wk2, partsA + 118784, 6, chunk, tid);
    }
  } else {
    cka_body(wa0, bk0, wa1, bk1, wa2, bk2, cka, tid);
  }
}

// ===========================================================================
// K0b: foldB (358) — LDS-staged WKA row; bpA inline in half==0 blocks
// ===========================================================================
__global__ __launch_bounds__(256) void fold_b(
    const float* __restrict__ partsA,
    const float* __restrict__ wp0, const float* __restrict__ bp0,
    const float* __restrict__ wp1, const float* __restrict__ bp1,
    const float* __restrict__ wp2, const float* __restrict__ bp2,
    float* __restrict__ WXA, float* __restrict__ bpA)
{
  __shared__ float lds[256];
  const int bid = blockIdx.x, tid = threadIdx.x;
  if (bid < 18)
    foldB_body<3>(lds, partsA, wp0, bp0, WXA, bpA,
                  bid >> 1, bid & 1, tid);
  else if (bid < 116)
    foldB_body<7>(lds, partsA + 18432, wp1, bp1, WXA + 6144, bpA + 121,
                  (bid - 18) >> 1, (bid - 18) & 1, tid);
  else
    foldB_body<11>(lds, partsA + 118784, wp2, bp2, WXA + 34816, bpA + 242,
                   (bid - 116) >> 1, (bid - 116) & 1, tid);
}

// ===========================================================================
// K2: gemm h1 (192)  ||  rcomp (768)
// ===========================================================================
__global__ __launch_bounds__(256) void k2_kernel(
    const float* __restrict__ x, const float* __restrict__ w1,
    const float* __restrict__ b1, const float* __restrict__ WXA,
    float* __restrict__ hall, float* __restrict__ rpart)
{
  __shared__ __align__(16) float smem[6400];
  const int bid = blockIdx.x, tid = threadIdx.x;
  if (bid < 192) {
    const int tx = bid % 3, oy = (bid / 3) % 8, n = bid / 24;
    gemm_body<false>(smem, w1, b1, x, hall, 512, 512, 512, 0,
                     tx * 64, oy * 32, n, tid);
  } else {
    const int rid = bid - 192;
    const int cc = rid % 32, n = (rid / 32) % 8, s = rid / 256;
    if (s == 0)      rcomp_body<1>(smem, x, WXA,         rpart,          cc, n, tid);
    else if (s == 1) rcomp_body<3>(smem, x, WXA + 6144,  rpart + 147456, cc, n, tid);
    else             rcomp_body<5>(smem, x, WXA + 34816, rpart + 491520, cc, n, tid);
  }
}

// ===========================================================================
// K3: rreduce (168)  ||  gconv (1536)
// ===========================================================================
__global__ __launch_bounds__(256) void k3_kernel(
    const float* __restrict__ rpart, const float* __restrict__ cka,
    const float* __restrict__ bpA, float* __restrict__ rbuf,
    const float* __restrict__ w2, const float* __restrict__ b2,
    float* __restrict__ hall)
{
  const int bid = blockIdx.x, tid = threadIdx.x;
  if (bid < 168) {
    rreduce_body(rpart, cka, bpA, rbuf, bid % 8, bid / 8, tid);
  } else {
    const int gid = bid - 168;
    gconv_body(hall, w2, b2, hall, gid % 3, (gid / 3) % 64, gid / 192, tid);
  }
}

// ===========================================================================
// K4: abuild (384)  ||  gemm w3 (192)
// ===========================================================================
__global__ __launch_bounds__(256) void k4_kernel(
    const float* __restrict__ rbuf,
    const float* __restrict__ ba0, const float* __restrict__ ba1,
    const float* __restrict__ ba2, float* __restrict__ At,
    const float* __restrict__ hall, const float* __restrict__ w3,
    const float* __restrict__ b3, float* __restrict__ xs)
{
  __shared__ __align__(16) float smem[6400];
  const int bid = blockIdx.x, tid = threadIdx.x;
  if (bid < 384) {
    abuild_body(rbuf, ba0, ba1, ba2, At, bid % 48, bid / 48, tid);
  } else {
    const int gid = bid - 384;
    const int tx = gid % 3, oy = (gid / 3) % 8, n = gid / 24;
    gemm_body<false>(smem, w3, b3, hall + 256 * 192, xs, 256, 512, 256, 0,
                     tx * 64, oy * 32, n, tid);
  }
}

// ===========================================================================
// K5: out0 = xs@A (192, At read transposed)  ||  transpose (288)
// ===========================================================================
__global__ __launch_bounds__(256) void k5_kernel(
    const float* __restrict__ xs, const float* __restrict__ At,
    float* __restrict__ out0, float* __restrict__ Aout)
{
  __shared__ __align__(16) float smem[6400];
  const int bid = blockIdx.x, tid = threadIdx.x;
  if (bid < 192) {
    const int tx = bid % 3, oy = (bid / 3) % 8, n = bid / 24;
    gemm_body<true>(smem, xs, nullptr, At, out0, 192, 0, 256, 256 * 192,
                    tx * 64, oy * 32, n, tid);
  } else {
    const int gid = bid - 192;
    transpose_body(smem, At, Aout, gid % 6, (gid / 6) % 6, gid / 36, tid);
  }
}

// ===========================================================================
extern "C" void kernel_launch(void* const* d_in, const int* in_sizes, int n_in,
                              void* d_out, int out_size, void* d_ws, size_t ws_size,
                              hipStream_t stream)
{
  const float* x   = (const float*)d_in[0];
  const float* wp0 = (const float*)d_in[1];
  const float* bp0 = (const float*)d_in[2];
  const float* wk0 = (const float*)d_in[3];
  const float* bk0 = (const float*)d_in[4];
  const float* wa0 = (const float*)d_in[5];
  const float* ba0 = (const float*)d_in[6];
  const float* wp1 = (const float*)d_in[7];
  const float* bp1 = (const float*)d_in[8];
  const float* wk1 = (const float*)d_in[9];
  const float* bk1 = (const float*)d_in[10];
  const float* wa1 = (const float*)d_in[11];
  const float* ba1 = (const float*)d_in[12];
  const float* wp2 = (const float*)d_in[13];
  const float* bp2 = (const float*)d_in[14];
  const float* wk2 = (const float*)d_in[15];
  const float* bk2 = (const float*)d_in[16];
  const float* wa2 = (const float*)d_in[17];
  const float* ba2 = (const float*)d_in[18];
  const float* w1  = (const float*)d_in[19];
  const float* b1  = (const float*)d_in[20];
  const float* w2  = (const float*)d_in[21];
  const float* b2  = (const float*)d_in[22];
  const float* w3  = (const float*)d_in[23];
  const float* b3  = (const float*)d_in[24];

  float* ws     = (float*)d_ws;
  float* hall   = ws;                         // [8][512][192]        =   786,432
  float* At     = hall   + 786432;            // [8][192][192]        =   294,912
  float* xs     = At     + 294912;            // [8][256][192]        =   393,216
  float* rpart  = xs     + 393216;            // [8][32][3+7+11][192] = 1,032,192
  float* rbuf   = rpart  + 1032192;           // [3][8][11][192]      =    50,688
  float* WXA    = rbuf   + 50688;             // [512]*(12+56+132)    =   102,400
  float* bpA    = WXA    + 102400;            // [3][121]             =       384
  float* cka    = bpA    + 384;               // [3][11] (pad 64)     =        64
  float* partsA = cka    + 64;                // 8*(9+49+121)*256     =   366,592
  float* out0   = (float*)d_out;              // [8][256][192]
  float* Aout   = out0 + 8 * 256 * 192;       // [8][192][192]

  // K0a: foldA partial WKA (barrier-free, coalesced wk)  +  cka
  fold_a<<<49, 256, 0, stream>>>(
      wa0, wk0, bk0, wa1, wk1, bk1, wa2, wk2, bk2, partsA, cka);

  // K0b: foldB -> WXA (LDS-staged row) + bpA
  fold_b<<<358, 256, 0, stream>>>(
      partsA, wp0, bp0, wp1, bp1, wp2, bp2, WXA, bpA);

  // K2: h1 = w1@x  ||  banded rcomp on x
  k2_kernel<<<192 + 768, 256, 0, stream>>>(x, w1, b1, WXA, hall, rpart);

  // K3: rreduce  ||  grouped conv + relu (h1 -> h2)
  k3_kernel<<<168 + 1536, 256, 0, stream>>>(rpart, cka, bpA, rbuf, w2, b2, hall);

  // K4: softmax A-build (wave-per-column)  ||  xs = w3@h2
  k4_kernel<<<384 + 192, 256, 0, stream>>>(rbuf, ba0, ba1, ba2, At,
                                           hall, w3, b3, xs);

  // K5: out0 = xs@A (transposed At staging)  ||  Aout = At^T
  k5_kernel<<<192 + 288, 256, 0, stream>>>(xs, At, out0, Aout);
}

// Round 16
// 71.931 us; speedup vs baseline: 15.2481x; 1.0010x over previous
//
#include <hip/hip_runtime.h>

#define T_LEN 192

// ===========================================================================
// ---- tiled GEMM body v3: Y[n,o,t] = sum_c W[o,c]*X[c,t] + B[o] ------------
// TRANSX=false: X[c,t] = Xg[(n*cstr + c)*192 + t]
// TRANSX=true : X[c,u] = Xg[(n*192 + u)*192 + c]   (At layout, transposed)
// Tile 32(o) x 64(t) x 64(c); 256 thr; micro 2o x 4t; register prefetch.
// LDS tiles XOR-swizzled (col' = col ^ 4*((row>>2)&7)) -> conflict-free
// scatter stores (old layout was ~8-way conflicted: 2.75M cycles in R12 p1).
// ===========================================================================
template<bool TRANSX>
__device__ __forceinline__ void gemm_body(
    float* smem,
    const float* __restrict__ W, const float* __restrict__ B,
    const float* __restrict__ X, float* __restrict__ Y,
    int cin, int cstr, int ostr, int wnstr,
    int t0, int o0, int n, int tid)
{
  float* Ws = smem;                                  // [64][32] swizzled
  float (*Xs)[68] = (float(*)[68])(smem + 2048);     // [64][68] swizzled
  const int to = tid >> 4, tt = tid & 15;
  float acc[2][4] = {};

  auto loadW = [&](int l, int c0) {
    int idx = l * 256 + tid; int rr = idx >> 4, c4 = idx & 15;
    return *reinterpret_cast<const float4*>(
        &W[(size_t)n * wnstr + (size_t)(o0 + rr) * cin + c0 + c4 * 4]);
  };
  auto loadX = [&](int l, int c0) {
    int idx = l * 256 + tid; int rr = idx >> 4, c4 = idx & 15;
    if (!TRANSX)
      return *reinterpret_cast<const float4*>(
          &X[((size_t)n * cstr + c0 + rr) * T_LEN + t0 + c4 * 4]);
    else
      return *reinterpret_cast<const float4*>(
          &X[((size_t)n * 192 + t0 + rr) * 192 + c0 + c4 * 4]);
  };

  float4 wreg[2], xreg[4];
#pragma unroll
  for (int l = 0; l < 2; ++l) wreg[l] = loadW(l, 0);
#pragma unroll
  for (int l = 0; l < 4; ++l) xreg[l] = loadX(l, 0);

  for (int c0 = 0; c0 < cin; c0 += 64) {
    __syncthreads();     // previous compute done reading LDS
    // ---- stage W: [c][o] scatter, swizzled ----
#pragma unroll
    for (int l = 0; l < 2; ++l) {
      int idx = l * 256 + tid;
      int rr = idx >> 4, c4 = idx & 15;          // rr = o-local, c4 = c-group
      float4 wv = wreg[l];
      const int sw = 4 * (c4 & 7);
      Ws[(c4 * 4 + 0) * 32 + (rr ^ sw)] = wv.x;
      Ws[(c4 * 4 + 1) * 32 + (rr ^ sw)] = wv.y;
      Ws[(c4 * 4 + 2) * 32 + (rr ^ sw)] = wv.z;
      Ws[(c4 * 4 + 3) * 32 + (rr ^ sw)] = wv.w;
    }
    // ---- stage X: [c][t], swizzled ----
#pragma unroll
    for (int l = 0; l < 4; ++l) {
      int idx = l * 256 + tid;
      int rr = idx >> 4, c4 = idx & 15;
      if (!TRANSX) {                              // rr = c, c4 = t-group
        *reinterpret_cast<float4*>(
            &Xs[rr][(c4 * 4) ^ (4 * ((rr >> 2) & 7))]) = xreg[l];
      } else {                                    // rr = t, c4 = c-group
        float4 xv = xreg[l];
        const int sw = 4 * (c4 & 7);
        Xs[c4 * 4 + 0][rr ^ sw] = xv.x;
        Xs[c4 * 4 + 1][rr ^ sw] = xv.y;
        Xs[c4 * 4 + 2][rr ^ sw] = xv.z;
        Xs[c4 * 4 + 3][rr ^ sw] = xv.w;
      }
    }
    if (c0 + 64 < cin) {   // prefetch next tile into registers
#pragma unroll
      for (int l = 0; l < 2; ++l) wreg[l] = loadW(l, c0 + 64);
#pragma unroll
      for (int l = 0; l < 4; ++l) xreg[l] = loadX(l, c0 + 64);
    }
    __syncthreads();
#pragma unroll
    for (int kk = 0; kk < 64; ++kk) {
      const int sw = 4 * ((kk >> 2) & 7);
      float2 a = *reinterpret_cast<const float2*>(
          &Ws[kk * 32 + ((to * 2) ^ sw)]);
      float4 b = *reinterpret_cast<const float4*>(
          &Xs[kk][(tt * 4) ^ sw]);
      acc[0][0] += a.x * b.x; acc[0][1] += a.x * b.y;
      acc[0][2] += a.x * b.z; acc[0][3] += a.x * b.w;
      acc[1][0] += a.y * b.x; acc[1][1] += a.y * b.y;
      acc[1][2] += a.y * b.z; acc[1][3] += a.y * b.w;
    }
  }
#pragma unroll
  for (int i = 0; i < 2; ++i) {
    float bi = B ? B[o0 + to * 2 + i] : 0.f;
    float4 v = make_float4(acc[i][0] + bi, acc[i][1] + bi,
                           acc[i][2] + bi, acc[i][3] + bi);
    *reinterpret_cast<float4*>(
        &Y[((size_t)n * ostr + o0 + to * 2 + i) * T_LEN + t0 + tt * 4]) = v;
  }
}

// ===========================================================================
// foldA: parts[chunk][j*K+i][c'] = sum_{c in 16-chunk} wa[c,j]*wk[c,c',i]
// Barrier-free: thread = c' (256), block = (s, chunk of 16 c, j-group).
// ===========================================================================
template<int K, int JN>
__device__ __forceinline__ void foldA_body(
    const float* __restrict__ wa, const float* __restrict__ wk,
    float* __restrict__ parts, int j0, int chunk, int tid)
{
  float acc[JN][K];
#pragma unroll
  for (int jj = 0; jj < JN; ++jj)
#pragma unroll
    for (int i = 0; i < K; ++i) acc[jj][i] = 0.f;

  const int c0 = chunk * 16;
  for (int c = c0; c < c0 + 16; ++c) {
    const float* base = &wk[((size_t)c * 256 + tid) * K];
    float v[K];
#pragma unroll
    for (int i = 0; i < K; ++i) v[i] = base[i];
    float w[JN];
#pragma unroll
    for (int jj = 0; jj < JN; ++jj) w[jj] = wa[c * K + j0 + jj];
#pragma unroll
    for (int jj = 0; jj < JN; ++jj)
#pragma unroll
      for (int i = 0; i < K; ++i) acc[jj][i] += w[jj] * v[i];
  }
#pragma unroll
  for (int jj = 0; jj < JN; ++jj)
#pragma unroll
    for (int i = 0; i < K; ++i)
      parts[((size_t)chunk * K * K + (j0 + jj) * K + i) * 256 + tid] = acc[jj][i];
}

// ---- cka[s,j] = sum_c wa[c,j]*bk[c] ---------------------------------------
__device__ __forceinline__ void cka_body(
    const float* __restrict__ wa0, const float* __restrict__ bk0,
    const float* __restrict__ wa1, const float* __restrict__ bk1,
    const float* __restrict__ wa2, const float* __restrict__ bk2,
    float* __restrict__ cka, int tid)
{
  if (tid >= 21) return;
  int s, j, K; const float *wa, *bk;
  if (tid < 3)       { s = 0; j = tid;      K = 3;  wa = wa0; bk = bk0; }
  else if (tid < 10) { s = 1; j = tid - 3;  K = 7;  wa = wa1; bk = bk1; }
  else               { s = 2; j = tid - 10; K = 11; wa = wa2; bk = bk2; }
  float acc = 0.f;
  for (int c = 0; c < 128; ++c) acc += wa[c * K + j] * bk[c];
  cka[s * 11 + j] = acc;
}

// ===========================================================================
// foldB: stage chunk-summed WKA row in LDS, then coalesced wp GEMV.
// half==0 block also computes bpA[ji] via LDS dot.
// ===========================================================================
template<int K>
__device__ __forceinline__ void foldB_body(
    float* lds, const float* __restrict__ parts, const float* __restrict__ wp,
    const float* __restrict__ bp, float* __restrict__ wxas,
    float* __restrict__ bpA_s, int ji, int half, int tid)
{
  constexpr int KP = (K + 3) & ~3;
  constexpr int K2 = K * K;
  float s = 0.f;
#pragma unroll
  for (int ch = 0; ch < 8; ++ch)
    s += parts[((size_t)(ch * K2 + ji)) * 256 + tid];
  lds[tid] = s;
  __syncthreads();

  const int cin = half * 256 + tid;
  float acc = 0.f;
  for (int c = 0; c < 256; ++c)
    acc += lds[c] * wp[(size_t)c * 512 + cin];
  const int j = ji / K, i = ji - j * K;
  wxas[(size_t)cin * K * KP + i * KP + j] = acc;

  if (half == 0 && tid == 0) {
    float b = 0.f;
    for (int c = 0; c < 256; ++c) b += lds[c] * bp[c];
    bpA_s[j * 11 + i] = b;
  }
}

// ===========================================================================
// rcomp: rpart[n,cc,j,t] = sum_{16ch,i} WXA[c,i,j]*xpad[n,c,t+i-A]
// ===========================================================================
template<int A>
__device__ __forceinline__ void rcomp_body(
    float* smem, const float* __restrict__ x, const float* __restrict__ WXAs,
    float* __restrict__ rps, int cc, int n, int tid)
{
  constexpr int K  = 2 * A + 1;
  constexpr int KP = (K + 3) & ~3;
  constexpr int WH = 192 + 2 * A;
  constexpr int WS = 204;
  float* Xs = smem;               // 16 x 204
  float* Wl = smem + 16 * WS;     // 16 x K x KP
  const int c0 = cc * 16;

  for (int idx = tid; idx < 16 * WH; idx += 256) {
    int c = idx / WH, p = idx - c * WH;
    int tau = p - A;
    Xs[c * WS + p] = (tau >= 0 && tau < 192)
        ? x[((size_t)n * 512 + c0 + c) * 192 + tau] : 0.f;
  }
  {
    const float4* wg = reinterpret_cast<const float4*>(WXAs + (size_t)c0 * K * KP);
    float4* wl = reinterpret_cast<float4*>(Wl);
    for (int idx = tid; idx < 16 * K * KP / 4; idx += 256) wl[idx] = wg[idx];
  }
  __syncthreads();

  const int w = tid >> 6, lane = tid & 63;
  const int csub = lane >> 4, tpos = lane & 15;
  const int tb = w * 48 + tpos * 3;

  float acc[K][3];
#pragma unroll
  for (int j = 0; j < K; ++j) { acc[j][0] = 0.f; acc[j][1] = 0.f; acc[j][2] = 0.f; }

#pragma unroll
  for (int c = 0; c < 4; ++c) {
    const int ch = csub * 4 + c;
    float win[K + 2];
#pragma unroll
    for (int p = 0; p < K + 2; ++p) win[p] = Xs[ch * WS + tb + p];
    const float* wr = &Wl[ch * K * KP];
#pragma unroll
    for (int i = 0; i < K; ++i) {
#pragma unroll
      for (int j = 0; j < K; ++j) {
        float wv = wr[i * KP + j];
        acc[j][0] += wv * win[i + 0];
        acc[j][1] += wv * win[i + 1];
        acc[j][2] += wv * win[i + 2];
      }
    }
  }
#pragma unroll
  for (int j = 0; j < K; ++j) {
#pragma unroll
    for (int q = 0; q < 3; ++q) {
      float v = acc[j][q];
      v += __shfl_xor(v, 16);
      v += __shfl_xor(v, 32);
      acc[j][q] = v;
    }
  }
  if (csub == 0) {
#pragma unroll
    for (int j = 0; j < K; ++j) {
      float* dst = &rps[(((size_t)n * 32 + cc) * K + j) * 192 + tb];
      dst[0] = acc[j][0]; dst[1] = acc[j][1]; dst[2] = acc[j][2];
    }
  }
}

// ---- rreduce: rbuf[s,n,j,t] = sum_cc rpart + cka + boundary bp term -------
__device__ __forceinline__ void rreduce_body(
    const float* __restrict__ rpart, const float* __restrict__ cka,
    const float* __restrict__ bpA, float* __restrict__ rbuf,
    int n, int sj, int t)
{
  if (t >= 192) return;
  const int s = sj < 3 ? 0 : sj < 10 ? 1 : 2;
  const int j = sj < 3 ? sj : sj < 10 ? sj - 3 : sj - 10;
  const int A = (s == 0) ? 1 : (s == 1) ? 3 : 5;
  const int K = 2 * A + 1;
  const int roff = (s == 0) ? 0 : (s == 1) ? 147456 : 491520;
  const float* rp = rpart + roff;
  float acc = cka[s * 11 + j];
#pragma unroll 8
  for (int cc = 0; cc < 32; ++cc)
    acc += rp[(((size_t)n * 32 + cc) * K + j) * 192 + t];
  for (int i = 0; i < K; ++i) {
    int tau = t + i - A;
    if (tau >= 0 && tau < 192) acc += bpA[s * 121 + j * 11 + i];
  }
  rbuf[((size_t)(s * 8 + n) * 11 + j) * 192 + t] = acc;
}

// ===========================================================================
// abuild: 1 wave = 1 softmax column u; 64 lanes x 3 t; shfl-only
// ===========================================================================
template<int A>
__device__ __forceinline__ float gather_val(const float* __restrict__ rs,
                                            int t, int u)
{
  constexpr int K = 2 * A + 1;
  float val = 0.f;
#pragma unroll
  for (int j = 0; j < K; ++j) {
    int tp = t + j - A;
    int d = tp - u;
    if (tp >= 0 && tp < 192 && d <= A && d >= -A) val += rs[j * 192 + tp];
  }
  return val;
}

__device__ __forceinline__ void abuild_body(
    const float* __restrict__ rbuf,
    const float* __restrict__ ba0, const float* __restrict__ ba1,
    const float* __restrict__ ba2, float* __restrict__ At,
    int ublk, int n, int tid)
{
  const int w = tid >> 6, lane = tid & 63;
  const int u = ublk * 4 + w;
  const int t0 = lane * 3;
  const float* r0 = rbuf + (size_t)(0 * 8 + n) * 11 * 192;
  const float* r1 = rbuf + (size_t)(1 * 8 + n) * 11 * 192;
  const float* r2 = rbuf + (size_t)(2 * 8 + n) * 11 * 192;
  float v0[3], v1[3], v2[3];
  const float b0 = ba0[0], b1 = ba1[0], b2 = ba2[0];
#pragma unroll
  for (int q = 0; q < 3; ++q) {
    v0[q] = b0 + gather_val<1>(r0, t0 + q, u);
    v1[q] = b1 + gather_val<3>(r1, t0 + q, u);
    v2[q] = b2 + gather_val<5>(r2, t0 + q, u);
  }
  float m0 = fmaxf(fmaxf(v0[0], v0[1]), v0[2]);
  float m1 = fmaxf(fmaxf(v1[0], v1[1]), v1[2]);
  float m2 = fmaxf(fmaxf(v2[0], v2[1]), v2[2]);
#pragma unroll
  for (int off = 32; off > 0; off >>= 1) {
    m0 = fmaxf(m0, __shfl_xor(m0, off));
    m1 = fmaxf(m1, __shfl_xor(m1, off));
    m2 = fmaxf(m2, __shfl_xor(m2, off));
  }
  float e0[3], e1[3], e2[3];
#pragma unroll
  for (int q = 0; q < 3; ++q) {
    e0[q] = __expf(v0[q] - m0);
    e1[q] = __expf(v1[q] - m1);
    e2[q] = __expf(v2[q] - m2);
  }
  float s0 = e0[0] + e0[1] + e0[2];
  float s1 = e1[0] + e1[1] + e1[2];
  float s2 = e2[0] + e2[1] + e2[2];
#pragma unroll
  for (int off = 32; off > 0; off >>= 1) {
    s0 += __shfl_xor(s0, off);
    s1 += __shfl_xor(s1, off);
    s2 += __shfl_xor(s2, off);
  }
  const float i0 = 1.f / s0, i1 = 1.f / s1, i2 = 1.f / s2;
  float* dst = &At[((size_t)n * 192 + u) * 192 + t0];
#pragma unroll
  for (int q = 0; q < 3; ++q)
    dst[q] = e0[q] * i0 + e1[q] * i1 + e2[q] * i2;
}

// ---- grouped conv (groups=32, K=3) + ReLU ---------------------------------
__device__ __forceinline__ void gconv_body(
    const float* __restrict__ hin, const float* __restrict__ w2,
    const float* __restrict__ b2, float* __restrict__ hout,
    int bx, int by, int n, int tid)
{
  const int t  = (tid & 63) + bx * 64;
  const int oc = (tid >> 6) + by * 4;
  const int g  = oc >> 3;
  float acc = b2[oc];
  for (int i = 0; i < 8; ++i) {
    const float* hrow = &hin[((size_t)n * 512 + g * 8 + i) * 192];
#pragma unroll
    for (int j = 0; j < 3; ++j) {
      int tt = t + j - 1;
      float hv = (tt >= 0 && tt < 192) ? hrow[tt] : 0.f;
      acc += w2[((size_t)oc * 8 + i) * 3 + j] * hv;
    }
  }
  hout[((size_t)n * 512 + 256 + oc) * 192 + t] = fmaxf(acc, 0.f);
}

// ---- At[n][u][t] -> Aout[n][t][u] ------------------------------------------
__device__ __forceinline__ void transpose_body(
    float* smem, const float* __restrict__ At, float* __restrict__ Aout,
    int bx, int by, int n, int tid)
{
  float (*tile)[33] = (float(*)[33])smem;
  const int xx = tid & 31, y = tid >> 5;
  for (int yy = y; yy < 32; yy += 8)
    tile[yy][xx] = At[((size_t)n * 192 + by * 32 + yy) * 192 + bx * 32 + xx];
  __syncthreads();
  for (int yy = y; yy < 32; yy += 8)
    Aout[((size_t)n * 192 + bx * 32 + yy) * 192 + by * 32 + xx] = tile[xx][yy];
}

// ===========================================================================
// K0a: foldA (48) + cka (1)
// ===========================================================================
__global__ __launch_bounds__(256) void fold_a(
    const float* __restrict__ wa0, const float* __restrict__ wk0,
    const float* __restrict__ bk0,
    const float* __restrict__ wa1, const float* __restrict__ wk1,
    const float* __restrict__ bk1,
    const float* __restrict__ wa2, const float* __restrict__ wk2,
    const float* __restrict__ bk2,
    float* __restrict__ partsA, float* __restrict__ cka)
{
  const int bid = blockIdx.x, tid = threadIdx.x;
  if (bid < 48) {
    const int s = bid >> 4, sub = bid & 15;
    const int chunk = sub >> 1, jg = sub & 1;
    if (s == 0) {
      if (jg == 0) foldA_body<3, 2>(wa0, wk0, partsA,          0, chunk, tid);
      else         foldA_body<3, 1>(wa0, wk0, partsA,          2, chunk, tid);
    } else if (s == 1) {
      if (jg == 0) foldA_body<7, 4>(wa1, wk1, partsA + 18432,  0, chunk, tid);
      else         foldA_body<7, 3>(wa1, wk1, partsA + 18432,  4, chunk, tid);
    } else {
      if (jg == 0) foldA_body<11, 6>(wa2, wk2, partsA + 118784, 0, chunk, tid);
      else         foldA_body<11, 5>(wa2, wk2, partsA + 118784, 6, chunk, tid);
    }
  } else {
    cka_body(wa0, bk0, wa1, bk1, wa2, bk2, cka, tid);
  }
}

// ===========================================================================
// K0b: foldB (358) — LDS-staged WKA row; bpA inline in half==0 blocks
// ===========================================================================
__global__ __launch_bounds__(256) void fold_b(
    const float* __restrict__ partsA,
    const float* __restrict__ wp0, const float* __restrict__ bp0,
    const float* __restrict__ wp1, const float* __restrict__ bp1,
    const float* __restrict__ wp2, const float* __restrict__ bp2,
    float* __restrict__ WXA, float* __restrict__ bpA)
{
  __shared__ float lds[256];
  const int bid = blockIdx.x, tid = threadIdx.x;
  if (bid < 18)
    foldB_body<3>(lds, partsA, wp0, bp0, WXA, bpA,
                  bid >> 1, bid & 1, tid);
  else if (bid < 116)
    foldB_body<7>(lds, partsA + 18432, wp1, bp1, WXA + 6144, bpA + 121,
                  (bid - 18) >> 1, (bid - 18) & 1, tid);
  else
    foldB_body<11>(lds, partsA + 118784, wp2, bp2, WXA + 34816, bpA + 242,
                   (bid - 116) >> 1, (bid - 116) & 1, tid);
}

// ===========================================================================
// K2: gemm h1 (192)  ||  rcomp (768)
// ===========================================================================
__global__ __launch_bounds__(256) void k2_kernel(
    const float* __restrict__ x, const float* __restrict__ w1,
    const float* __restrict__ b1, const float* __restrict__ WXA,
    float* __restrict__ hall, float* __restrict__ rpart)
{
  __shared__ __align__(16) float smem[6400];
  const int bid = blockIdx.x, tid = threadIdx.x;
  if (bid < 192) {
    const int tx = bid % 3, oy = (bid / 3) % 8, n = bid / 24;
    gemm_body<false>(smem, w1, b1, x, hall, 512, 512, 512, 0,
                     tx * 64, oy * 32, n, tid);
  } else {
    const int rid = bid - 192;
    const int cc = rid % 32, n = (rid / 32) % 8, s = rid / 256;
    if (s == 0)      rcomp_body<1>(smem, x, WXA,         rpart,          cc, n, tid);
    else if (s == 1) rcomp_body<3>(smem, x, WXA + 6144,  rpart + 147456, cc, n, tid);
    else             rcomp_body<5>(smem, x, WXA + 34816, rpart + 491520, cc, n, tid);
  }
}

// ===========================================================================
// K3: rreduce (168)  ||  gconv (1536)
// ===========================================================================
__global__ __launch_bounds__(256) void k3_kernel(
    const float* __restrict__ rpart, const float* __restrict__ cka,
    const float* __restrict__ bpA, float* __restrict__ rbuf,
    const float* __restrict__ w2, const float* __restrict__ b2,
    float* __restrict__ hall)
{
  const int bid = blockIdx.x, tid = threadIdx.x;
  if (bid < 168) {
    rreduce_body(rpart, cka, bpA, rbuf, bid % 8, bid / 8, tid);
  } else {
    const int gid = bid - 168;
    gconv_body(hall, w2, b2, hall, gid % 3, (gid / 3) % 64, gid / 192, tid);
  }
}

// ===========================================================================
// K4: abuild (384)  ||  gemm w3 (192)
// ===========================================================================
__global__ __launch_bounds__(256) void k4_kernel(
    const float* __restrict__ rbuf,
    const float* __restrict__ ba0, const float* __restrict__ ba1,
    const float* __restrict__ ba2, float* __restrict__ At,
    const float* __restrict__ hall, const float* __restrict__ w3,
    const float* __restrict__ b3, float* __restrict__ xs)
{
  __shared__ __align__(16) float smem[6400];
  const int bid = blockIdx.x, tid = threadIdx.x;
  if (bid < 384) {
    abuild_body(rbuf, ba0, ba1, ba2, At, bid % 48, bid / 48, tid);
  } else {
    const int gid = bid - 384;
    const int tx = gid % 3, oy = (gid / 3) % 8, n = gid / 24;
    gemm_body<false>(smem, w3, b3, hall + 256 * 192, xs, 256, 512, 256, 0,
                     tx * 64, oy * 32, n, tid);
  }
}

// ===========================================================================
// K5: out0 = xs@A (192, At read transposed)  ||  transpose (288)
// ===========================================================================
__global__ __launch_bounds__(256) void k5_kernel(
    const float* __restrict__ xs, const float* __restrict__ At,
    float* __restrict__ out0, float* __restrict__ Aout)
{
  __shared__ __align__(16) float smem[6400];
  const int bid = blockIdx.x, tid = threadIdx.x;
  if (bid < 192) {
    const int tx = bid % 3, oy = (bid / 3) % 8, n = bid / 24;
    gemm_body<true>(smem, xs, nullptr, At, out0, 192, 0, 256, 256 * 192,
                    tx * 64, oy * 32, n, tid);
  } else {
    const int gid = bid - 192;
    transpose_body(smem, At, Aout, gid % 6, (gid / 6) % 6, gid / 36, tid);
  }
}

// ===========================================================================
extern "C" void kernel_launch(void* const* d_in, const int* in_sizes, int n_in,
                              void* d_out, int out_size, void* d_ws, size_t ws_size,
                              hipStream_t stream)
{
  const float* x   = (const float*)d_in[0];
  const float* wp0 = (const float*)d_in[1];
  const float* bp0 = (const float*)d_in[2];
  const float* wk0 = (const float*)d_in[3];
  const float* bk0 = (const float*)d_in[4];
  const float* wa0 = (const float*)d_in[5];
  const float* ba0 = (const float*)d_in[6];
  const float* wp1 = (const float*)d_in[7];
  const float* bp1 = (const float*)d_in[8];
  const float* wk1 = (const float*)d_in[9];
  const float* bk1 = (const float*)d_in[10];
  const float* wa1 = (const float*)d_in[11];
  const float* ba1 = (const float*)d_in[12];
  const float* wp2 = (const float*)d_in[13];
  const float* bp2 = (const float*)d_in[14];
  const float* wk2 = (const float*)d_in[15];
  const float* bk2 = (const float*)d_in[16];
  const float* wa2 = (const float*)d_in[17];
  const float* ba2 = (const float*)d_in[18];
  const float* w1  = (const float*)d_in[19];
  const float* b1  = (const float*)d_in[20];
  const float* w2  = (const float*)d_in[21];
  const float* b2  = (const float*)d_in[22];
  const float* w3  = (const float*)d_in[23];
  const float* b3  = (const float*)d_in[24];

  float* ws     = (float*)d_ws;
  float* hall   = ws;                         // [8][512][192]        =   786,432
  float* At     = hall   + 786432;            // [8][192][192]        =   294,912
  float* xs     = At     + 294912;            // [8][256][192]        =   393,216
  float* rpart  = xs     + 393216;            // [8][32][3+7+11][192] = 1,032,192
  float* rbuf   = rpart  + 1032192;           // [3][8][11][192]      =    50,688
  float* WXA    = rbuf   + 50688;             // [512]*(12+56+132)    =   102,400
  float* bpA    = WXA    + 102400;            // [3][121]             =       384
  float* cka    = bpA    + 384;               // [3][11] (pad 64)     =        64
  float* partsA = cka    + 64;                // 8*(9+49+121)*256     =   366,592
  float* out0   = (float*)d_out;              // [8][256][192]
  float* Aout   = out0 + 8 * 256 * 192;       // [8][192][192]

  // K0a: foldA partial WKA (barrier-free, coalesced wk)  +  cka
  fold_a<<<49, 256, 0, stream>>>(
      wa0, wk0, bk0, wa1, wk1, bk1, wa2, wk2, bk2, partsA, cka);

  // K0b: foldB -> WXA (LDS-staged row) + bpA
  fold_b<<<358, 256, 0, stream>>>(
      partsA, wp0, bp0, wp1, bp1, wp2, bp2, WXA, bpA);

  // K2: h1 = w1@x  ||  banded rcomp on x
  k2_kernel<<<192 + 768, 256, 0, stream>>>(x, w1, b1, WXA, hall, rpart);

  // K3: rreduce  ||  grouped conv + relu (h1 -> h2)
  k3_kernel<<<168 + 1536, 256, 0, stream>>>(rpart, cka, bpA, rbuf, w2, b2, hall);

  // K4: softmax A-build (wave-per-column)  ||  xs = w3@h2
  k4_kernel<<<384 + 192, 256, 0, stream>>>(rbuf, ba0, ba1, ba2, At,
                                           hall, w3, b3, xs);

  // K5: out0 = xs@A (transposed At staging)  ||  Aout = At^T
  k5_kernel<<<192 + 288, 256, 0, stream>>>(xs, At, out0, Aout);
}